// Round 6
// baseline (365.555 us; speedup 1.0000x reference)
//
#include <hip/hip_runtime.h>
#include <cstdint>

typedef unsigned short u16;
typedef _Float16 half8 __attribute__((ext_vector_type(8)));
typedef float floatx4 __attribute__((ext_vector_type(4)));

#define BB 2048
#define UU 1024
#define HUx 256
#define O_H  0
#define O_C  (BB*UU)
#define O_HO (2*BB*UU)
#define O_HC (2*BB*UU + BB*HUx)
#define MFMAH __builtin_amdgcn_mfma_f32_16x16x32_f16

// raw barrier: ds-write visibility (lgkmcnt) without the __syncthreads vmcnt(0) drain,
// so prefetched global loads stay in flight across barriers (T3/T4 mechanism).
// sched_barrier(0) pins ordering (rule #18: hipcc can hoist reg-only ops past asm waitcnt).
#define LBAR() do { \
    asm volatile("s_waitcnt lgkmcnt(0)\n\ts_barrier" ::: "memory"); \
    __builtin_amdgcn_sched_barrier(0); \
} while (0)

__device__ __forceinline__ float bf2f(u16 u) {
    union { uint32_t i; float f; } v; v.i = ((uint32_t)u) << 16; return v.f;
}
__device__ __forceinline__ u16 f2bf(float f) {
    union { float f; uint32_t i; } v; v.f = f;
    uint32_t r = v.i + 0x7fffu + ((v.i >> 16) & 1u);
    return (u16)(r >> 16);
}
__device__ __forceinline__ u16 f2h(float f) {
    _Float16 h = (_Float16)f; u16 u; __builtin_memcpy(&u, &h, 2); return u;
}
__device__ __forceinline__ float sigf(float x) { return 1.f / (1.f + expf(-x)); }
__device__ __forceinline__ float ldmix(const void* p, size_t i, int isbf) {
    return isbf ? bf2f(((const u16*)p)[i]) : ((const float*)p)[i];
}
// load input element (bf16 or fp32) -> fp16 bits
__device__ __forceinline__ u16 ld2h(const void* p, size_t i, int isbf) {
    return f2h(ldmix(p, i, isbf));
}

// split staging: load-to-regs / write-to-LDS (prefetch pipeline; 256-thread blocks)
__device__ __forceinline__ void ld128(half8 r[2], const u16* src, int row0, int ldK,
                                      int k0, int tid) {
    #pragma unroll
    for (int i = 0; i < 2; i++) {
        int v = tid + 256 * i;
        r[i] = *(const half8*)(src + (size_t)(row0 + (v >> 2)) * ldK + k0 + (v & 3) * 8);
    }
}
__device__ __forceinline__ void ld64(half8& r, const u16* src, int row0, int ldK,
                                     int k0, int tid) {
    r = *(const half8*)(src + (size_t)(row0 + (tid >> 2)) * ldK + k0 + (tid & 3) * 8);
}
__device__ __forceinline__ void wr128(u16* lds, const half8 r[2], int tid) {
    #pragma unroll
    for (int i = 0; i < 2; i++) {
        int v = tid + 256 * i;
        *(half8*)&lds[(v >> 2) * 40 + (v & 3) * 8] = r[i];
    }
}
__device__ __forceinline__ void wr64(u16* lds, half8 r, int tid) {
    *(half8*)&lds[(tid >> 2) * 40 + (tid & 3) * 8] = r;
}

// direct global->reg A-fragment load for 16x16x32 MFMA (r6):
// lane reads 16B at row (row0 + t*16 + (lane&15)), col k0 + (lane>>4)*8.
// Wave-collectively this covers 16 rows x 64B = full cache lines (coalesced).
__device__ __forceinline__ void ldA4(half8 r[4], const u16* src, int row0, int ldK,
                                     int k0, int mr, int kq) {
    #pragma unroll
    for (int t = 0; t < 4; t++)
        r[t] = *(const half8*)(src + (size_t)(row0 + t * 16 + mr) * ldK + k0 + kq);
}

// ---------------- dtype detection (1 = bf16, 0 = fp32) ----------------
__global__ void detect_dtype(const u16* __restrict__ raw, int* __restrict__ flag) {
    u16 u = raw[2 * threadIdx.x];
    int e = (u >> 7) & 0xFF;
    unsigned long long m = __ballot(e >= 100 && e <= 134);
    if (threadIdx.x == 0) *flag = (__popcll(m) >= 32) ? 1 : 0;
}

// ---------------- merged input conversion -> fp16: inputs->xh, main_h->mh, hyper_h->hh ----------------
__global__ void cvt_all(const void* __restrict__ xs, const void* __restrict__ ms,
                        const void* __restrict__ hs, u16* __restrict__ xh,
                        u16* __restrict__ mh, u16* __restrict__ hh, const int* __restrict__ flag) {
    int i = blockIdx.x * 256 + threadIdx.x;
    int isbf = *flag;
    const void* src; u16* dst; int t;
    if (i < 262144)      { src = xs; dst = xh; t = i; }
    else if (i < 524288) { src = ms; dst = mh; t = i - 262144; }
    else                 { src = hs; dst = hh; t = i - 524288; }  // < 65536
    #pragma unroll
    for (int j = 0; j < 8; j++)
        dst[(size_t)t * 8 + j] = ld2h(src, (size_t)t * 8 + j, isbf);
}

// ---------------- transpose(+convert->fp16): out[c*ostride+ocol+r]=in[r*C+c] ----------------
__global__ void transpose_cvt(const void* __restrict__ in, u16* __restrict__ out,
                              int R, int C, int ostride, int ocol,
                              const int* __restrict__ flag) {
    __shared__ u16 th[32][33];
    int isbf = *flag;
    int c0 = blockIdx.x * 32, r0 = blockIdx.y * 32;
    int tx = threadIdx.x, ty = threadIdx.y;  // block (32,8)
    #pragma unroll
    for (int i = 0; i < 32; i += 8)
        th[ty + i][tx] = ld2h(in, (size_t)(r0 + ty + i) * C + c0 + tx, isbf);
    __syncthreads();
    #pragma unroll
    for (int i = 0; i < 32; i += 8)
        out[(size_t)(c0 + ty + i) * ostride + ocol + r0 + tx] = th[tx][ty + i];
}

// z-dim variant: up to 3 (in,out) pairs with identical geometry
__global__ void transpose_z(const void* __restrict__ i0, const void* __restrict__ i1,
                            const void* __restrict__ i2, u16* __restrict__ o0,
                            u16* __restrict__ o1, u16* __restrict__ o2,
                            int R, int C, int ostride, const int* __restrict__ flag) {
    __shared__ u16 th[32][33];
    const void* in = (blockIdx.z == 0) ? i0 : (blockIdx.z == 1) ? i1 : i2;
    u16* out = (blockIdx.z == 0) ? o0 : (blockIdx.z == 1) ? o1 : o2;
    int isbf = *flag;
    int c0 = blockIdx.x * 32, r0 = blockIdx.y * 32;
    int tx = threadIdx.x, ty = threadIdx.y;
    #pragma unroll
    for (int i = 0; i < 32; i += 8)
        th[ty + i][tx] = ld2h(in, (size_t)(r0 + ty + i) * C + c0 + tx, isbf);
    __syncthreads();
    #pragma unroll
    for (int i = 0; i < 32; i += 8)
        out[(size_t)(c0 + ty + i) * ostride + r0 + tx] = th[tx][ty + i];
}

// ---------------- hyper GEMM (fp16): z = x@Wx + mh@Wm + hh@Wh ----------------
// r4: r3-proven register-prefetch + LBAR pipeline, unified step counter s in [0,72)
// across the 3 A-phases, and split-K x2 (blockIdx.z) -> 512 blocks = 2/CU overlap.
// Partial sums to zbuf halves; hyper_cell adds them. (r5 measured: dropped out of top-5.)
__device__ __forceinline__ void gh_load(half8 pA[2], half8& pB,
                                        const u16* xh, const u16* mh, const u16* hh,
                                        const u16* BT, int bm, int bn, int s, int tid) {
    const u16* Ap; int ldA, kA;
    if (s < 32)      { Ap = xh; ldA = 1024; kA = s * 32; }
    else if (s < 64) { Ap = mh; ldA = 1024; kA = (s - 32) * 32; }
    else             { Ap = hh; ldA = 256;  kA = (s - 64) * 32; }
    ld128(pA, Ap, bm, ldA, kA, tid);
    ld64(pB, BT, bn, 2304, s * 32, tid);
}

__global__ __launch_bounds__(256) void gemm_hyper(const u16* __restrict__ xh,
                                                  const u16* __restrict__ mh,
                                                  const u16* __restrict__ hh,
                                                  const u16* __restrict__ BT,
                                                  float* __restrict__ z) {
    __shared__ __align__(16) u16 sA[128 * 40];
    __shared__ __align__(16) u16 sB[64 * 40];
    int tid = threadIdx.x, lane = tid & 63, wave = tid >> 6;
    int wm = (wave & 1) * 64, wn = (wave >> 1) * 32;
    int bm = blockIdx.y * 128, bn = blockIdx.x * 64;
    int s0 = blockIdx.z * 36, s1 = s0 + 36;
    floatx4 acc[4][2] = {};
    int mr = lane & 15, kq = (lane >> 4) * 8;

    half8 pA[2]; half8 pB;
    gh_load(pA, pB, xh, mh, hh, BT, bm, bn, s0, tid);
    wr128(sA, pA, tid); wr64(sB, pB, tid);
    gh_load(pA, pB, xh, mh, hh, BT, bm, bn, s0 + 1, tid);
    LBAR();

    #pragma unroll 1
    for (int s = s0; s < s1; s++) {
        half8 a[4], b[2];
        #pragma unroll
        for (int t = 0; t < 4; t++) a[t] = *(const half8*)&sA[(wm + t * 16 + mr) * 40 + kq];
        #pragma unroll
        for (int t = 0; t < 2; t++) b[t] = *(const half8*)&sB[(wn + t * 16 + mr) * 40 + kq];
        #pragma unroll
        for (int tm = 0; tm < 4; tm++)
            #pragma unroll
            for (int tn = 0; tn < 2; tn++)
                acc[tm][tn] = MFMAH(a[tm], b[tn], acc[tm][tn], 0, 0, 0);
        LBAR();  // all waves done reading LDS -> safe to overwrite
        if (s < s1 - 1) {
            wr128(sA, pA, tid); wr64(sB, pB, tid);
            if (s < s1 - 2)
                gh_load(pA, pB, xh, mh, hh, BT, bm, bn, s + 2, tid);
            LBAR();  // writes visible
        }
    }

    float* zp = z + (size_t)blockIdx.z * 2048 * 1024;
    #pragma unroll
    for (int tm = 0; tm < 4; tm++)
        #pragma unroll
        for (int tn = 0; tn < 2; tn++) {
            int col = bn + wn + tn * 16 + (lane & 15);
            #pragma unroll
            for (int rr = 0; rr < 4; rr++) {
                int row = bm + wm + tm * 16 + (lane >> 4) * 4 + rr;
                zp[(size_t)row * 1024 + col] = acc[tm][tn][rr];
            }
        }
}

// ---------------- hyper LSTM cell (sums split-K halves); ho stored fp16 ----------------
__global__ void hyper_cell(const float* __restrict__ z, const void* __restrict__ hyper_c,
                           const void* __restrict__ hyper_bias, void* __restrict__ out,
                           u16* __restrict__ ho16, const int* __restrict__ flag) {
    int isbf = *flag;
    int t = blockIdx.x * 256 + threadIdx.x;
    int k = t & 255;
    const float* zr  = z + (size_t)(t >> 8) * 1024;
    const float* zr2 = zr + (size_t)2048 * 1024;
    float hi = zr[k]       + zr2[k]       + ldmix(hyper_bias, k, isbf);
    float hf = zr[k + 256] + zr2[k + 256] + ldmix(hyper_bias, k + 256, isbf);
    float hg = zr[k + 512] + zr2[k + 512] + ldmix(hyper_bias, k + 512, isbf);
    float ho = zr[k + 768] + zr2[k + 768] + ldmix(hyper_bias, k + 768, isbf);
    float c  = ldmix(hyper_c, t, isbf);
    float cn = sigf(hf) * c + sigf(hi) * tanhf(hg);
    float hout = sigf(ho) * tanhf(cn);
    ho16[t] = f2h(hout);
    if (isbf) {
        ((u16*)out)[O_HO + t] = f2bf(hout);
        ((u16*)out)[O_HC + t] = f2bf(cn);
    } else {
        ((float*)out)[O_HO + t] = hout;
        ((float*)out)[O_HC + t] = cn;
    }
}

// ---------------- fused gates GEMM (fp16, 5 acc sets) -> gates_pre fp16 ----------------
// block 128M x 64N, waves 2(M)x2(N), wave tile 64x32 PER SET.
// r5 post-mortem: LDS-pipe-bound — 12 ds_read_b128 + 6 ds_write_b128 per wave-step
// (~864 cyc LDS/block-step vs ~80 cyc MFMA/SIMD) = ~63% of kernel time; A-frags are
// 2/3 of it. r6: A-fragments load DIRECTLY global->reg (wave-level cache-line
// coalesced, see ldA4), double-buffered in regs (even/odd unroll, static indexing).
// LDS keeps only B staging (15KB) + the r3-proven LBAR pipeline (also paces waves
// so the x2 intra-block A duplication hits L1).
__global__ __launch_bounds__(256, 2) void mega_fused(
    const u16* __restrict__ xh, const u16* __restrict__ mh, const u16* __restrict__ ho16,
    const u16* __restrict__ kT, const u16* __restrict__ rkT,
    const u16* __restrict__ dxT, const u16* __restrict__ dhT, const u16* __restrict__ dbT,
    const void* __restrict__ bias, const void* __restrict__ dx_b,
    const void* __restrict__ dh_b, const void* __restrict__ db_b,
    u16* __restrict__ gp, const int* __restrict__ flag) {
    __shared__ __align__(16) u16 sB1[64 * 40];
    __shared__ __align__(16) u16 sB2[64 * 40];
    __shared__ __align__(16) u16 sB3[64 * 40];
    int isbf = *flag;
    int tid = threadIdx.x, lane = tid & 63, wave = tid >> 6;
    int wm = (wave & 1) * 64, wn = (wave >> 1) * 32;
    int bm = blockIdx.y * 128, bn = blockIdx.x * 64;
    floatx4 apx[4][2] = {}, aph[4][2] = {}, adx[4][2] = {}, adh[4][2] = {}, adb[4][2] = {};
    int mr = lane & 15, kq = (lane >> 4) * 8;
    int arow = bm + wm;

    half8 nB1a, nB2a, nB3a;
    half8 axA[4], amA[4], axB[4], amB[4];

    // ---- phase 1 prologue: stage B tile0, prefetch B tile1, load A frags step0 ----
    ld64(nB1a, kT,  bn, 1024, 0, tid);
    ld64(nB2a, rkT, bn, 1024, 0, tid);
    wr64(sB1, nB1a, tid); wr64(sB2, nB2a, tid);
    ld64(nB1a, kT,  bn, 1024, 32, tid);
    ld64(nB2a, rkT, bn, 1024, 32, tid);
    ldA4(axA, xh, arow, 1024, 0, mr, kq);
    ldA4(amA, mh, arow, 1024, 0, mr, kq);
    LBAR();

    // one 32-K step: prefetch A(K0+32) into AXN/AMN, MFMA with AXC/AMC, pipeline B
    #define P1_STEP(AXC, AMC, AXN, AMN, K0)                                    \
    do {                                                                       \
        if ((K0) + 32 < 1024) {                                                \
            ldA4(AXN, xh, arow, 1024, (K0) + 32, mr, kq);                      \
            ldA4(AMN, mh, arow, 1024, (K0) + 32, mr, kq);                      \
        }                                                                      \
        half8 bk[2], br[2];                                                    \
        _Pragma("unroll")                                                      \
        for (int t = 0; t < 2; t++) {                                          \
            int rb = (wn + t * 16 + mr) * 40 + kq;                             \
            bk[t] = *(const half8*)&sB1[rb];                                   \
            br[t] = *(const half8*)&sB2[rb];                                   \
        }                                                                      \
        _Pragma("unroll")                                                      \
        for (int tm = 0; tm < 4; tm++)                                         \
            _Pragma("unroll")                                                  \
            for (int tn = 0; tn < 2; tn++) {                                   \
                apx[tm][tn] = MFMAH((AXC)[tm], bk[tn], apx[tm][tn], 0, 0, 0);  \
                aph[tm][tn] = MFMAH((AMC)[tm], br[tn], aph[tm][tn], 0, 0, 0);  \
            }                                                                  \
        LBAR();                                                                \
        if ((K0) < 992) {                                                      \
            wr64(sB1, nB1a, tid); wr64(sB2, nB2a, tid);                        \
            if ((K0) < 960) {                                                  \
                ld64(nB1a, kT,  bn, 1024, (K0) + 64, tid);                     \
                ld64(nB2a, rkT, bn, 1024, (K0) + 64, tid);                     \
            } else {                                                           \
                ld64(nB1a, dxT, bn, 256, 0, tid);                              \
                ld64(nB2a, dhT, bn, 256, 0, tid);                              \
                ld64(nB3a, dbT, bn, 256, 0, tid);                              \
            }                                                                  \
            LBAR();                                                            \
        }                                                                      \
    } while (0)

    #pragma unroll 1
    for (int k0 = 0; k0 < 1024; k0 += 64) {
        P1_STEP(axA, amA, axB, amB, k0);
        P1_STEP(axB, amB, axA, amA, k0 + 32);
    }
    #undef P1_STEP

    // ---- phase 2 prologue: B tile0 regs from phase-1 tail; write, prefetch tile1 ----
    wr64(sB1, nB1a, tid); wr64(sB2, nB2a, tid); wr64(sB3, nB3a, tid);
    ld64(nB1a, dxT, bn, 256, 32, tid);
    ld64(nB2a, dhT, bn, 256, 32, tid);
    ld64(nB3a, dbT, bn, 256, 32, tid);
    ldA4(axA, ho16, arow, 256, 0, mr, kq);
    LBAR();

    #define P2_STEP(AC, AN, K0)                                                \
    do {                                                                       \
        if ((K0) + 32 < 256) ldA4(AN, ho16, arow, 256, (K0) + 32, mr, kq);     \
        half8 bx[2], bh[2], bb[2];                                             \
        _Pragma("unroll")                                                      \
        for (int t = 0; t < 2; t++) {                                          \
            int rb = (wn + t * 16 + mr) * 40 + kq;                             \
            bx[t] = *(const half8*)&sB1[rb];                                   \
            bh[t] = *(const half8*)&sB2[rb];                                   \
            bb[t] = *(const half8*)&sB3[rb];                                   \
        }                                                                      \
        _Pragma("unroll")                                                      \
        for (int tm = 0; tm < 4; tm++)                                         \
            _Pragma("unroll")                                                  \
            for (int tn = 0; tn < 2; tn++) {                                   \
                adx[tm][tn] = MFMAH((AC)[tm], bx[tn], adx[tm][tn], 0, 0, 0);   \
                adh[tm][tn] = MFMAH((AC)[tm], bh[tn], adh[tm][tn], 0, 0, 0);   \
                adb[tm][tn] = MFMAH((AC)[tm], bb[tn], adb[tm][tn], 0, 0, 0);   \
            }                                                                  \
        LBAR();                                                                \
        if ((K0) < 224) {                                                      \
            wr64(sB1, nB1a, tid); wr64(sB2, nB2a, tid); wr64(sB3, nB3a, tid);  \
            if ((K0) < 192) {                                                  \
                ld64(nB1a, dxT, bn, 256, (K0) + 64, tid);                      \
                ld64(nB2a, dhT, bn, 256, (K0) + 64, tid);                      \
                ld64(nB3a, dbT, bn, 256, (K0) + 64, tid);                      \
            }                                                                  \
            LBAR();                                                            \
        }                                                                      \
    } while (0)

    #pragma unroll 1
    for (int k0 = 0; k0 < 256; k0 += 64) {
        P2_STEP(axA, axB, k0);
        P2_STEP(axB, axA, k0 + 32);
    }
    #undef P2_STEP

    // epilogue: g = (adx+dxb)*(apx+bias) + (adh+dhb)*aph + (adb+dbb), stored fp16
    #pragma unroll
    for (int tn = 0; tn < 2; tn++) {
        int col = bn + wn + tn * 16 + (lane & 15);
        float bv  = ldmix(bias, col, isbf);
        float dxb = ldmix(dx_b, col, isbf);
        float dhb = ldmix(dh_b, col, isbf);
        float dbb = ldmix(db_b, col, isbf);
        #pragma unroll
        for (int tm = 0; tm < 4; tm++) {
            #pragma unroll
            for (int rr = 0; rr < 4; rr++) {
                int row = bm + wm + tm * 16 + (lane >> 4) * 4 + rr;
                float px = apx[tm][tn][rr] + bv;
                float ph = aph[tm][tn][rr];
                float dx = adx[tm][tn][rr] + dxb;
                float dh = adh[tm][tn][rr] + dhb;
                float db = adb[tm][tn][rr] + dbb;
                gp[(size_t)row * 4096 + col] = f2h(dx * px + dh * ph + db);
            }
        }
    }
}

// ---------------- LN(4096) -> gates -> c_new -> LN(1024) -> h_new ----------------
__device__ __forceinline__ void block_reduce2(float& a, float& b, float* red) {
    #pragma unroll
    for (int o = 32; o > 0; o >>= 1) {
        a += __shfl_down(a, o, 64);
        b += __shfl_down(b, o, 64);
    }
    int lane = threadIdx.x & 63, w = threadIdx.x >> 6;
    if (lane == 0) { red[w] = a; red[4 + w] = b; }
    __syncthreads();
    a = red[0] + red[1] + red[2] + red[3];
    b = red[4] + red[5] + red[6] + red[7];
    __syncthreads();
}

__global__ __launch_bounds__(256) void ln_main(const u16* __restrict__ gp,
                                               const void* __restrict__ main_c,
                                               void* __restrict__ out,
                                               const int* __restrict__ flag) {
    __shared__ float sPre[4096];
    __shared__ float sC[1024];
    __shared__ float red[8];
    int isbf = *flag;
    int b = blockIdx.x, tid = threadIdx.x;
    const u16* g = gp + (size_t)b * 4096;
    float s = 0.f, q = 0.f;
    for (int j0 = tid * 8; j0 < 4096; j0 += 2048) {
        half8 v = *(const half8*)(g + j0);
        #pragma unroll
        for (int e = 0; e < 8; e++) {
            float f = (float)v[e];
            sPre[j0 + e] = f; s += f; q += f * f;
        }
    }
    block_reduce2(s, q, red);
    float mean = s * (1.f / 4096.f);
    float var = q * (1.f / 4096.f) - mean * mean;
    float rs = rsqrtf(var + 1e-3f);
    float s2 = 0.f, q2 = 0.f;
    for (int u = tid; u < 1024; u += 256) {
        float gi = (sPre[u] - mean) * rs;
        float gf = (sPre[u + 1024] - mean) * rs;
        float gg = (sPre[u + 2048] - mean) * rs;
        float c = ldmix(main_c, (size_t)b * 1024 + u, isbf);
        float cn = sigf(gf) * c + sigf(gi) * tanhf(gg);
        sC[u] = cn;
        if (isbf) ((u16*)out)[O_C + (size_t)b * 1024 + u] = f2bf(cn);
        else      ((float*)out)[O_C + (size_t)b * 1024 + u] = cn;
        s2 += cn; q2 += cn * cn;
    }
    block_reduce2(s2, q2, red);
    float m2 = s2 * (1.f / 1024.f);
    float v2 = q2 * (1.f / 1024.f) - m2 * m2;
    float rs2 = rsqrtf(v2 + 1e-3f);
    for (int u = tid; u < 1024; u += 256) {
        float go = (sPre[u + 3072] - mean) * rs;
        float hn = sigf(go) * tanhf((sC[u] - m2) * rs2);
        if (isbf) ((u16*)out)[O_H + (size_t)b * 1024 + u] = f2bf(hn);
        else      ((float*)out)[O_H + (size_t)b * 1024 + u] = hn;
    }
}

// ---------------- launcher ----------------
extern "C" void kernel_launch(void* const* d_in, const int* in_sizes, int n_in,
                              void* d_out, int out_size, void* d_ws, size_t ws_size,
                              hipStream_t stream) {
    (void)in_sizes; (void)n_in; (void)out_size; (void)ws_size;
    const void* inputs   = d_in[0];
    const void* main_h   = d_in[1];
    const void* main_c   = d_in[2];
    const void* hyper_h  = d_in[3];
    const void* hyper_c  = d_in[4];
    const void* kernel_w = d_in[5];
    const void* rec_w    = d_in[6];
    const void* bias     = d_in[7];
    const void* hyper_k  = d_in[8];
    const void* hyper_rk = d_in[9];
    const void* hyper_b  = d_in[10];
    const void* dx_w = d_in[11];
    const void* dx_b = d_in[12];
    const void* dh_w = d_in[13];
    const void* dh_b = d_in[14];
    const void* db_w = d_in[15];
    const void* db_b = d_in[16];
    char* ws = (char*)d_ws;
    const size_t MB = 1024 * 1024;

    // workspace layout, NO overlays (ws >= 100 MB proven in r6/r7)
    int* flag = (int*)ws;
    size_t off = 256;
    u16* xh  = (u16*)(ws + off); off += 4 * MB;            // [2048,1024] fp16
    u16* mh  = (u16*)(ws + off); off += 4 * MB;            // [2048,1024] fp16
    u16* hh  = (u16*)(ws + off); off += 1 * MB;            // [2048,256]  fp16
    u16* ho  = (u16*)(ws + off); off += 1 * MB;            // [2048,256]  fp16
    u16* kT  = (u16*)(ws + off); off += 8 * MB;            // [4096,1024] fp16
    u16* rkT = (u16*)(ws + off); off += 8 * MB;            // [4096,1024] fp16
    u16* dxT = (u16*)(ws + off); off += 2 * MB;            // [4096,256]  fp16
    u16* dhT = (u16*)(ws + off); off += 2 * MB;
    u16* dbT = (u16*)(ws + off); off += 2 * MB;
    u16* BTh = (u16*)(ws + off); off += (size_t)1024 * 2304 * 2;  // 4.5 MB
    float* zbuf = (float*)(ws + off); off += 16 * MB;      // [2, 2048,1024] fp32 (split-K halves)
    u16* gp    = (u16*)(ws + off); off += 16 * MB;         // [2048,4096] fp16

    detect_dtype<<<1, 64, 0, stream>>>((const u16*)inputs, flag);
    cvt_all<<<2304, 256, 0, stream>>>(inputs, main_h, hyper_h, xh, mh, hh, flag);

    dim3 tblk(32, 8);
    transpose_cvt<<<dim3(32, 64), tblk, 0, stream>>>(hyper_k, BTh, 2048, 1024, 2304, 0, flag);
    transpose_cvt<<<dim3(32, 8),  tblk, 0, stream>>>(hyper_rk, BTh, 256, 1024, 2304, 2048, flag);
    transpose_z<<<dim3(128, 32, 2), tblk, 0, stream>>>(kernel_w, rec_w, rec_w,
                                                       kT, rkT, rkT, 1024, 4096, 1024, flag);
    transpose_z<<<dim3(128, 8, 3), tblk, 0, stream>>>(dx_w, dh_w, db_w,
                                                      dxT, dhT, dbT, 256, 4096, 256, flag);

    gemm_hyper<<<dim3(16, 16, 2), 256, 0, stream>>>(xh, mh, hh, BTh, zbuf);
    hyper_cell<<<2048, 256, 0, stream>>>(zbuf, hyper_c, hyper_b, d_out, ho, flag);
    mega_fused<<<dim3(64, 16), 256, 0, stream>>>(xh, mh, ho, kT, rkT, dxT, dhT, dbT,
                                                 bias, dx_b, dh_b, db_b, gp, flag);
    ln_main<<<2048, 256, 0, stream>>>(gp, main_c, d_out, flag);
}

// Round 7
// 293.094 us; speedup vs baseline: 1.2472x; 1.2472x over previous
//
#include <hip/hip_runtime.h>
#include <cstdint>

typedef unsigned short u16;
typedef _Float16 half8 __attribute__((ext_vector_type(8)));
typedef float floatx4 __attribute__((ext_vector_type(4)));

#define BB 2048
#define UU 1024
#define HUx 256
#define O_H  0
#define O_C  (BB*UU)
#define O_HO (2*BB*UU)
#define O_HC (2*BB*UU + BB*HUx)
#define MFMAH __builtin_amdgcn_mfma_f32_16x16x32_f16

// raw barrier: ds-write visibility (lgkmcnt) without the __syncthreads vmcnt(0) drain,
// so prefetched global loads stay in flight across barriers (T3/T4 mechanism).
// sched_barrier(0) pins ordering (rule #18: hipcc can hoist reg-only ops past asm waitcnt).
#define LBAR() do { \
    asm volatile("s_waitcnt lgkmcnt(0)\n\ts_barrier" ::: "memory"); \
    __builtin_amdgcn_sched_barrier(0); \
} while (0)

__device__ __forceinline__ float bf2f(u16 u) {
    union { uint32_t i; float f; } v; v.i = ((uint32_t)u) << 16; return v.f;
}
__device__ __forceinline__ u16 f2bf(float f) {
    union { float f; uint32_t i; } v; v.f = f;
    uint32_t r = v.i + 0x7fffu + ((v.i >> 16) & 1u);
    return (u16)(r >> 16);
}
__device__ __forceinline__ u16 f2h(float f) {
    _Float16 h = (_Float16)f; u16 u; __builtin_memcpy(&u, &h, 2); return u;
}
__device__ __forceinline__ float sigf(float x) { return 1.f / (1.f + expf(-x)); }
__device__ __forceinline__ float ldmix(const void* p, size_t i, int isbf) {
    return isbf ? bf2f(((const u16*)p)[i]) : ((const float*)p)[i];
}
// load input element (bf16 or fp32) -> fp16 bits
__device__ __forceinline__ u16 ld2h(const void* p, size_t i, int isbf) {
    return f2h(ldmix(p, i, isbf));
}

// split staging: load-to-regs / write-to-LDS (prefetch pipeline; 256-thread blocks)
__device__ __forceinline__ void ld128(half8 r[2], const u16* src, int row0, int ldK,
                                      int k0, int tid) {
    #pragma unroll
    for (int i = 0; i < 2; i++) {
        int v = tid + 256 * i;
        r[i] = *(const half8*)(src + (size_t)(row0 + (v >> 2)) * ldK + k0 + (v & 3) * 8);
    }
}
__device__ __forceinline__ void ld64(half8& r, const u16* src, int row0, int ldK,
                                     int k0, int tid) {
    r = *(const half8*)(src + (size_t)(row0 + (tid >> 2)) * ldK + k0 + (tid & 3) * 8);
}
__device__ __forceinline__ void wr128(u16* lds, const half8 r[2], int tid) {
    #pragma unroll
    for (int i = 0; i < 2; i++) {
        int v = tid + 256 * i;
        *(half8*)&lds[(v >> 2) * 40 + (v & 3) * 8] = r[i];
    }
}
__device__ __forceinline__ void wr64(u16* lds, half8 r, int tid) {
    *(half8*)&lds[(tid >> 2) * 40 + (tid & 3) * 8] = r;
}

// ---------------- dtype detection (1 = bf16, 0 = fp32) ----------------
__global__ void detect_dtype(const u16* __restrict__ raw, int* __restrict__ flag) {
    u16 u = raw[2 * threadIdx.x];
    int e = (u >> 7) & 0xFF;
    unsigned long long m = __ballot(e >= 100 && e <= 134);
    if (threadIdx.x == 0) *flag = (__popcll(m) >= 32) ? 1 : 0;
}

// ---------------- merged input conversion -> fp16: inputs->xh, main_h->mh, hyper_h->hh ----------------
__global__ void cvt_all(const void* __restrict__ xs, const void* __restrict__ ms,
                        const void* __restrict__ hs, u16* __restrict__ xh,
                        u16* __restrict__ mh, u16* __restrict__ hh, const int* __restrict__ flag) {
    int i = blockIdx.x * 256 + threadIdx.x;
    int isbf = *flag;
    const void* src; u16* dst; int t;
    if (i < 262144)      { src = xs; dst = xh; t = i; }
    else if (i < 524288) { src = ms; dst = mh; t = i - 262144; }
    else                 { src = hs; dst = hh; t = i - 524288; }  // < 65536
    #pragma unroll
    for (int j = 0; j < 8; j++)
        dst[(size_t)t * 8 + j] = ld2h(src, (size_t)t * 8 + j, isbf);
}

// ---------------- transpose(+convert->fp16): out[c*ostride+ocol+r]=in[r*C+c] ----------------
__global__ void transpose_cvt(const void* __restrict__ in, u16* __restrict__ out,
                              int R, int C, int ostride, int ocol,
                              const int* __restrict__ flag) {
    __shared__ u16 th[32][33];
    int isbf = *flag;
    int c0 = blockIdx.x * 32, r0 = blockIdx.y * 32;
    int tx = threadIdx.x, ty = threadIdx.y;  // block (32,8)
    #pragma unroll
    for (int i = 0; i < 32; i += 8)
        th[ty + i][tx] = ld2h(in, (size_t)(r0 + ty + i) * C + c0 + tx, isbf);
    __syncthreads();
    #pragma unroll
    for (int i = 0; i < 32; i += 8)
        out[(size_t)(c0 + ty + i) * ostride + ocol + r0 + tx] = th[tx][ty + i];
}

// z-dim variant: up to 3 (in,out) pairs with identical geometry
__global__ void transpose_z(const void* __restrict__ i0, const void* __restrict__ i1,
                            const void* __restrict__ i2, u16* __restrict__ o0,
                            u16* __restrict__ o1, u16* __restrict__ o2,
                            int R, int C, int ostride, const int* __restrict__ flag) {
    __shared__ u16 th[32][33];
    const void* in = (blockIdx.z == 0) ? i0 : (blockIdx.z == 1) ? i1 : i2;
    u16* out = (blockIdx.z == 0) ? o0 : (blockIdx.z == 1) ? o1 : o2;
    int isbf = *flag;
    int c0 = blockIdx.x * 32, r0 = blockIdx.y * 32;
    int tx = threadIdx.x, ty = threadIdx.y;
    #pragma unroll
    for (int i = 0; i < 32; i += 8)
        th[ty + i][tx] = ld2h(in, (size_t)(r0 + ty + i) * C + c0 + tx, isbf);
    __syncthreads();
    #pragma unroll
    for (int i = 0; i < 32; i += 8)
        out[(size_t)(c0 + ty + i) * ostride + r0 + tx] = th[tx][ty + i];
}

// ---------------- hyper GEMM (fp16): z = x@Wx + mh@Wm + hh@Wh ----------------
// r4: r3-proven register-prefetch + LBAR pipeline, unified step counter s in [0,72)
// across the 3 A-phases, and split-K x2 (blockIdx.z) -> 512 blocks = 2/CU overlap.
// Partial sums to zbuf halves; hyper_cell adds them. (r5 measured: dropped out of top-5.)
__device__ __forceinline__ void gh_load(half8 pA[2], half8& pB,
                                        const u16* xh, const u16* mh, const u16* hh,
                                        const u16* BT, int bm, int bn, int s, int tid) {
    const u16* Ap; int ldA, kA;
    if (s < 32)      { Ap = xh; ldA = 1024; kA = s * 32; }
    else if (s < 64) { Ap = mh; ldA = 1024; kA = (s - 32) * 32; }
    else             { Ap = hh; ldA = 256;  kA = (s - 64) * 32; }
    ld128(pA, Ap, bm, ldA, kA, tid);
    ld64(pB, BT, bn, 2304, s * 32, tid);
}

__global__ __launch_bounds__(256) void gemm_hyper(const u16* __restrict__ xh,
                                                  const u16* __restrict__ mh,
                                                  const u16* __restrict__ hh,
                                                  const u16* __restrict__ BT,
                                                  float* __restrict__ z) {
    __shared__ __align__(16) u16 sA[128 * 40];
    __shared__ __align__(16) u16 sB[64 * 40];
    int tid = threadIdx.x, lane = tid & 63, wave = tid >> 6;
    int wm = (wave & 1) * 64, wn = (wave >> 1) * 32;
    int bm = blockIdx.y * 128, bn = blockIdx.x * 64;
    int s0 = blockIdx.z * 36, s1 = s0 + 36;
    floatx4 acc[4][2] = {};
    int mr = lane & 15, kq = (lane >> 4) * 8;

    half8 pA[2]; half8 pB;
    gh_load(pA, pB, xh, mh, hh, BT, bm, bn, s0, tid);
    wr128(sA, pA, tid); wr64(sB, pB, tid);
    gh_load(pA, pB, xh, mh, hh, BT, bm, bn, s0 + 1, tid);
    LBAR();

    #pragma unroll 1
    for (int s = s0; s < s1; s++) {
        half8 a[4], b[2];
        #pragma unroll
        for (int t = 0; t < 4; t++) a[t] = *(const half8*)&sA[(wm + t * 16 + mr) * 40 + kq];
        #pragma unroll
        for (int t = 0; t < 2; t++) b[t] = *(const half8*)&sB[(wn + t * 16 + mr) * 40 + kq];
        #pragma unroll
        for (int tm = 0; tm < 4; tm++)
            #pragma unroll
            for (int tn = 0; tn < 2; tn++)
                acc[tm][tn] = MFMAH(a[tm], b[tn], acc[tm][tn], 0, 0, 0);
        LBAR();  // all waves done reading LDS -> safe to overwrite
        if (s < s1 - 1) {
            wr128(sA, pA, tid); wr64(sB, pB, tid);
            if (s < s1 - 2)
                gh_load(pA, pB, xh, mh, hh, BT, bm, bn, s + 2, tid);
            LBAR();  // writes visible
        }
    }

    float* zp = z + (size_t)blockIdx.z * 2048 * 1024;
    #pragma unroll
    for (int tm = 0; tm < 4; tm++)
        #pragma unroll
        for (int tn = 0; tn < 2; tn++) {
            int col = bn + wn + tn * 16 + (lane & 15);
            #pragma unroll
            for (int rr = 0; rr < 4; rr++) {
                int row = bm + wm + tm * 16 + (lane >> 4) * 4 + rr;
                zp[(size_t)row * 1024 + col] = acc[tm][tn][rr];
            }
        }
}

// ---------------- hyper LSTM cell (sums split-K halves); ho stored fp16 ----------------
__global__ void hyper_cell(const float* __restrict__ z, const void* __restrict__ hyper_c,
                           const void* __restrict__ hyper_bias, void* __restrict__ out,
                           u16* __restrict__ ho16, const int* __restrict__ flag) {
    int isbf = *flag;
    int t = blockIdx.x * 256 + threadIdx.x;
    int k = t & 255;
    const float* zr  = z + (size_t)(t >> 8) * 1024;
    const float* zr2 = zr + (size_t)2048 * 1024;
    float hi = zr[k]       + zr2[k]       + ldmix(hyper_bias, k, isbf);
    float hf = zr[k + 256] + zr2[k + 256] + ldmix(hyper_bias, k + 256, isbf);
    float hg = zr[k + 512] + zr2[k + 512] + ldmix(hyper_bias, k + 512, isbf);
    float ho = zr[k + 768] + zr2[k + 768] + ldmix(hyper_bias, k + 768, isbf);
    float c  = ldmix(hyper_c, t, isbf);
    float cn = sigf(hf) * c + sigf(hi) * tanhf(hg);
    float hout = sigf(ho) * tanhf(cn);
    ho16[t] = f2h(hout);
    if (isbf) {
        ((u16*)out)[O_HO + t] = f2bf(hout);
        ((u16*)out)[O_HC + t] = f2bf(cn);
    } else {
        ((float*)out)[O_HO + t] = hout;
        ((float*)out)[O_HC + t] = cn;
    }
}

// ---------------- fused gates GEMM (fp16, 5 acc sets) -> gates_pre fp16 ----------------
// block 128M x 64N, waves 2(M)x2(N), wave tile 64x32 PER SET.
// r6 post-mortem: direct global->reg A (no LDS) REGRESSED 91.6->157us — global-load
// latency on the per-step critical path; ds_reads were never the problem. REVERTED.
// r7: r3 dataflow (A,B via LDS, reg-prefetch dist 1) + TRUE LDS DOUBLE-BUFFER:
// read buf[p], write next tile to buf[p^1], ONE LBAR per step (was two) — ds_writes
// now overlap MFMA. Parity safety: step k-1's reads of buf[p^1] end at the barrier
// admitting step k. Phase1 last step stages phase2 tile0 into the opposite buffer.
// Buffer layout (u16 offsets): ph1 A1@0 A2@5120 B1@10240 B2@12800;
//                              ph2 A@0 B1@5120 B2@7680 B3@10240.
__global__ __launch_bounds__(256, 2) void mega_fused(
    const u16* __restrict__ xh, const u16* __restrict__ mh, const u16* __restrict__ ho16,
    const u16* __restrict__ kT, const u16* __restrict__ rkT,
    const u16* __restrict__ dxT, const u16* __restrict__ dhT, const u16* __restrict__ dbT,
    const void* __restrict__ bias, const void* __restrict__ dx_b,
    const void* __restrict__ dh_b, const void* __restrict__ db_b,
    u16* __restrict__ gp, const int* __restrict__ flag) {
    __shared__ __align__(16) u16 S[2][15360];
    int isbf = *flag;
    int tid = threadIdx.x, lane = tid & 63, wave = tid >> 6;
    int wm = (wave & 1) * 64, wn = (wave >> 1) * 32;
    int bm = blockIdx.y * 128, bn = blockIdx.x * 64;
    floatx4 apx[4][2] = {}, aph[4][2] = {}, adx[4][2] = {}, adh[4][2] = {}, adb[4][2] = {};
    int mr = lane & 15, kq = (lane >> 4) * 8;

    half8 nA1[2], nA2[2], nB1, nB2, nB3;

    // ---- prologue: tile0 -> regs -> buf0 ; tile1 -> regs ; barrier ----
    ld128(nA1, xh,  bm, 1024, 0, tid);
    ld128(nA2, mh,  bm, 1024, 0, tid);
    ld64(nB1, kT,  bn, 1024, 0, tid);
    ld64(nB2, rkT, bn, 1024, 0, tid);
    wr128(S[0], nA1, tid); wr128(S[0] + 5120, nA2, tid);
    wr64(S[0] + 10240, nB1, tid); wr64(S[0] + 12800, nB2, tid);
    ld128(nA1, xh,  bm, 1024, 32, tid);
    ld128(nA2, mh,  bm, 1024, 32, tid);
    ld64(nB1, kT,  bn, 1024, 32, tid);
    ld64(nB2, rkT, bn, 1024, 32, tid);
    LBAR();

    // ---- phase 1: px = x@kT, ph = mh@rkT  (K=1024), 1 barrier/step ----
    #pragma unroll 1
    for (int k0 = 0; k0 < 1024; k0 += 32) {
        int p = (k0 >> 5) & 1;
        const u16* C = S[p];
        u16* N = S[p ^ 1];
        half8 ax[4], am[4], bk[2], br[2];
        #pragma unroll
        for (int t = 0; t < 4; t++) {
            int ra = (wm + t * 16 + mr) * 40 + kq;
            ax[t] = *(const half8*)&C[ra];
            am[t] = *(const half8*)&C[5120 + ra];
        }
        #pragma unroll
        for (int t = 0; t < 2; t++) {
            int rb = (wn + t * 16 + mr) * 40 + kq;
            bk[t] = *(const half8*)&C[10240 + rb];
            br[t] = *(const half8*)&C[12800 + rb];
        }
        // stage next tile (in regs) into the other buffer — overlaps MFMA below
        if (k0 < 992) {
            wr128(N, nA1, tid); wr128(N + 5120, nA2, tid);
            wr64(N + 10240, nB1, tid); wr64(N + 12800, nB2, tid);
        } else {
            // last ph1 step: stage PHASE-2 tile0 (loaded at k0==960), phase2 layout
            wr128(N, nA1, tid);
            wr64(N + 5120, nB1, tid); wr64(N + 7680, nB2, tid); wr64(N + 10240, nB3, tid);
        }
        // prefetch tile k0+64 into regs
        if (k0 < 960) {
            ld128(nA1, xh,  bm, 1024, k0 + 64, tid);
            ld128(nA2, mh,  bm, 1024, k0 + 64, tid);
            ld64(nB1, kT,  bn, 1024, k0 + 64, tid);
            ld64(nB2, rkT, bn, 1024, k0 + 64, tid);
        } else if (k0 == 960) {
            ld128(nA1, ho16, bm, 256, 0, tid);
            ld64(nB1, dxT, bn, 256, 0, tid);
            ld64(nB2, dhT, bn, 256, 0, tid);
            ld64(nB3, dbT, bn, 256, 0, tid);
        } else {  // k0 == 992: phase-2 tile1
            ld128(nA1, ho16, bm, 256, 32, tid);
            ld64(nB1, dxT, bn, 256, 32, tid);
            ld64(nB2, dhT, bn, 256, 32, tid);
            ld64(nB3, dbT, bn, 256, 32, tid);
        }
        #pragma unroll
        for (int tm = 0; tm < 4; tm++)
            #pragma unroll
            for (int tn = 0; tn < 2; tn++) {
                apx[tm][tn] = MFMAH(ax[tm], bk[tn], apx[tm][tn], 0, 0, 0);
                aph[tm][tn] = MFMAH(am[tm], br[tn], aph[tm][tn], 0, 0, 0);
            }
        LBAR();
    }

    // ---- phase 2: d_* = ho @ {dxT,dhT,dbT}  (K=256); A shared by 3 sets ----
    #pragma unroll 1
    for (int k0 = 0; k0 < 256; k0 += 32) {
        int p = (k0 >> 5) & 1;
        const u16* C = S[p];
        u16* N = S[p ^ 1];
        half8 a[4], bx[2], bh[2], bb[2];
        #pragma unroll
        for (int t = 0; t < 4; t++) {
            int ra = (wm + t * 16 + mr) * 40 + kq;
            a[t] = *(const half8*)&C[ra];
        }
        #pragma unroll
        for (int t = 0; t < 2; t++) {
            int rb = (wn + t * 16 + mr) * 40 + kq;
            bx[t] = *(const half8*)&C[5120 + rb];
            bh[t] = *(const half8*)&C[7680 + rb];
            bb[t] = *(const half8*)&C[10240 + rb];
        }
        if (k0 < 224) {
            wr128(N, nA1, tid);
            wr64(N + 5120, nB1, tid); wr64(N + 7680, nB2, tid); wr64(N + 10240, nB3, tid);
        }
        if (k0 < 192) {
            ld128(nA1, ho16, bm, 256, k0 + 64, tid);
            ld64(nB1, dxT, bn, 256, k0 + 64, tid);
            ld64(nB2, dhT, bn, 256, k0 + 64, tid);
            ld64(nB3, dbT, bn, 256, k0 + 64, tid);
        }
        #pragma unroll
        for (int tm = 0; tm < 4; tm++)
            #pragma unroll
            for (int tn = 0; tn < 2; tn++) {
                adx[tm][tn] = MFMAH(a[tm], bx[tn], adx[tm][tn], 0, 0, 0);
                adh[tm][tn] = MFMAH(a[tm], bh[tn], adh[tm][tn], 0, 0, 0);
                adb[tm][tn] = MFMAH(a[tm], bb[tn], adb[tm][tn], 0, 0, 0);
            }
        LBAR();
    }

    // epilogue: g = (adx+dxb)*(apx+bias) + (adh+dhb)*aph + (adb+dbb), stored fp16
    #pragma unroll
    for (int tn = 0; tn < 2; tn++) {
        int col = bn + wn + tn * 16 + (lane & 15);
        float bv  = ldmix(bias, col, isbf);
        float dxb = ldmix(dx_b, col, isbf);
        float dhb = ldmix(dh_b, col, isbf);
        float dbb = ldmix(db_b, col, isbf);
        #pragma unroll
        for (int tm = 0; tm < 4; tm++) {
            #pragma unroll
            for (int rr = 0; rr < 4; rr++) {
                int row = bm + wm + tm * 16 + (lane >> 4) * 4 + rr;
                float px = apx[tm][tn][rr] + bv;
                float ph = aph[tm][tn][rr];
                float dx = adx[tm][tn][rr] + dxb;
                float dh = adh[tm][tn][rr] + dhb;
                float db = adb[tm][tn][rr] + dbb;
                gp[(size_t)row * 4096 + col] = f2h(dx * px + dh * ph + db);
            }
        }
    }
}

// ---------------- LN(4096) -> gates -> c_new -> LN(1024) -> h_new ----------------
__device__ __forceinline__ void block_reduce2(float& a, float& b, float* red) {
    #pragma unroll
    for (int o = 32; o > 0; o >>= 1) {
        a += __shfl_down(a, o, 64);
        b += __shfl_down(b, o, 64);
    }
    int lane = threadIdx.x & 63, w = threadIdx.x >> 6;
    if (lane == 0) { red[w] = a; red[4 + w] = b; }
    __syncthreads();
    a = red[0] + red[1] + red[2] + red[3];
    b = red[4] + red[5] + red[6] + red[7];
    __syncthreads();
}

__global__ __launch_bounds__(256) void ln_main(const u16* __restrict__ gp,
                                               const void* __restrict__ main_c,
                                               void* __restrict__ out,
                                               const int* __restrict__ flag) {
    __shared__ float sPre[4096];
    __shared__ float sC[1024];
    __shared__ float red[8];
    int isbf = *flag;
    int b = blockIdx.x, tid = threadIdx.x;
    const u16* g = gp + (size_t)b * 4096;
    float s = 0.f, q = 0.f;
    for (int j0 = tid * 8; j0 < 4096; j0 += 2048) {
        half8 v = *(const half8*)(g + j0);
        #pragma unroll
        for (int e = 0; e < 8; e++) {
            float f = (float)v[e];
            sPre[j0 + e] = f; s += f; q += f * f;
        }
    }
    block_reduce2(s, q, red);
    float mean = s * (1.f / 4096.f);
    float var = q * (1.f / 4096.f) - mean * mean;
    float rs = rsqrtf(var + 1e-3f);
    float s2 = 0.f, q2 = 0.f;
    for (int u = tid; u < 1024; u += 256) {
        float gi = (sPre[u] - mean) * rs;
        float gf = (sPre[u + 1024] - mean) * rs;
        float gg = (sPre[u + 2048] - mean) * rs;
        float c = ldmix(main_c, (size_t)b * 1024 + u, isbf);
        float cn = sigf(gf) * c + sigf(gi) * tanhf(gg);
        sC[u] = cn;
        if (isbf) ((u16*)out)[O_C + (size_t)b * 1024 + u] = f2bf(cn);
        else      ((float*)out)[O_C + (size_t)b * 1024 + u] = cn;
        s2 += cn; q2 += cn * cn;
    }
    block_reduce2(s2, q2, red);
    float m2 = s2 * (1.f / 1024.f);
    float v2 = q2 * (1.f / 1024.f) - m2 * m2;
    float rs2 = rsqrtf(v2 + 1e-3f);
    for (int u = tid; u < 1024; u += 256) {
        float go = (sPre[u + 3072] - mean) * rs;
        float hn = sigf(go) * tanhf((sC[u] - m2) * rs2);
        if (isbf) ((u16*)out)[O_H + (size_t)b * 1024 + u] = f2bf(hn);
        else      ((float*)out)[O_H + (size_t)b * 1024 + u] = hn;
    }
}

// ---------------- launcher ----------------
extern "C" void kernel_launch(void* const* d_in, const int* in_sizes, int n_in,
                              void* d_out, int out_size, void* d_ws, size_t ws_size,
                              hipStream_t stream) {
    (void)in_sizes; (void)n_in; (void)out_size; (void)ws_size;
    const void* inputs   = d_in[0];
    const void* main_h   = d_in[1];
    const void* main_c   = d_in[2];
    const void* hyper_h  = d_in[3];
    const void* hyper_c  = d_in[4];
    const void* kernel_w = d_in[5];
    const void* rec_w    = d_in[6];
    const void* bias     = d_in[7];
    const void* hyper_k  = d_in[8];
    const void* hyper_rk = d_in[9];
    const void* hyper_b  = d_in[10];
    const void* dx_w = d_in[11];
    const void* dx_b = d_in[12];
    const void* dh_w = d_in[13];
    const void* dh_b = d_in[14];
    const void* db_w = d_in[15];
    const void* db_b = d_in[16];
    char* ws = (char*)d_ws;
    const size_t MB = 1024 * 1024;

    // workspace layout, NO overlays (ws >= 100 MB proven in r6/r7)
    int* flag = (int*)ws;
    size_t off = 256;
    u16* xh  = (u16*)(ws + off); off += 4 * MB;            // [2048,1024] fp16
    u16* mh  = (u16*)(ws + off); off += 4 * MB;            // [2048,1024] fp16
    u16* hh  = (u16*)(ws + off); off += 1 * MB;            // [2048,256]  fp16
    u16* ho  = (u16*)(ws + off); off += 1 * MB;            // [2048,256]  fp16
    u16* kT  = (u16*)(ws + off); off += 8 * MB;            // [4096,1024] fp16
    u16* rkT = (u16*)(ws + off); off += 8 * MB;            // [4096,1024] fp16
    u16* dxT = (u16*)(ws + off); off += 2 * MB;            // [4096,256]  fp16
    u16* dhT = (u16*)(ws + off); off += 2 * MB;
    u16* dbT = (u16*)(ws + off); off += 2 * MB;
    u16* BTh = (u16*)(ws + off); off += (size_t)1024 * 2304 * 2;  // 4.5 MB
    float* zbuf = (float*)(ws + off); off += 16 * MB;      // [2, 2048,1024] fp32 (split-K halves)
    u16* gp    = (u16*)(ws + off); off += 16 * MB;         // [2048,4096] fp16

    detect_dtype<<<1, 64, 0, stream>>>((const u16*)inputs, flag);
    cvt_all<<<2304, 256, 0, stream>>>(inputs, main_h, hyper_h, xh, mh, hh, flag);

    dim3 tblk(32, 8);
    transpose_cvt<<<dim3(32, 64), tblk, 0, stream>>>(hyper_k, BTh, 2048, 1024, 2304, 0, flag);
    transpose_cvt<<<dim3(32, 8),  tblk, 0, stream>>>(hyper_rk, BTh, 256, 1024, 2304, 2048, flag);
    transpose_z<<<dim3(128, 32, 2), tblk, 0, stream>>>(kernel_w, rec_w, rec_w,
                                                       kT, rkT, rkT, 1024, 4096, 1024, flag);
    transpose_z<<<dim3(128, 8, 3), tblk, 0, stream>>>(dx_w, dh_w, db_w,
                                                      dxT, dhT, dbT, 256, 4096, 256, flag);

    gemm_hyper<<<dim3(16, 16, 2), 256, 0, stream>>>(xh, mh, hh, BTh, zbuf);
    hyper_cell<<<2048, 256, 0, stream>>>(zbuf, hyper_c, hyper_b, d_out, ho, flag);
    mega_fused<<<dim3(64, 16), 256, 0, stream>>>(xh, mh, ho, kT, rkT, dxT, dhT, dbT,
                                                 bias, dx_b, dh_b, db_b, gp, flag);
    ln_main<<<2048, 256, 0, stream>>>(gp, main_c, d_out, flag);
}

// Round 8
// 288.645 us; speedup vs baseline: 1.2665x; 1.0154x over previous
//
#include <hip/hip_runtime.h>
#include <cstdint>

typedef unsigned short u16;
typedef _Float16 half8 __attribute__((ext_vector_type(8)));
typedef float floatx4 __attribute__((ext_vector_type(4)));

#define BB 2048
#define UU 1024
#define HUx 256
#define O_H  0
#define O_C  (BB*UU)
#define O_HO (2*BB*UU)
#define O_HC (2*BB*UU + BB*HUx)
#define MFMAH __builtin_amdgcn_mfma_f32_16x16x32_f16

// raw barrier: ds-write visibility (lgkmcnt) without the __syncthreads vmcnt(0) drain,
// so prefetched global loads stay in flight across barriers (T3/T4 mechanism).
// sched_barrier(0) pins ordering (rule #18: hipcc can hoist reg-only ops past asm waitcnt).
#define LBAR() do { \
    asm volatile("s_waitcnt lgkmcnt(0)\n\ts_barrier" ::: "memory"); \
    __builtin_amdgcn_sched_barrier(0); \
} while (0)

__device__ __forceinline__ float bf2f(u16 u) {
    union { uint32_t i; float f; } v; v.i = ((uint32_t)u) << 16; return v.f;
}
__device__ __forceinline__ u16 f2bf(float f) {
    union { float f; uint32_t i; } v; v.f = f;
    uint32_t r = v.i + 0x7fffu + ((v.i >> 16) & 1u);
    return (u16)(r >> 16);
}
__device__ __forceinline__ u16 f2h(float f) {
    _Float16 h = (_Float16)f; u16 u; __builtin_memcpy(&u, &h, 2); return u;
}
__device__ __forceinline__ float sigf(float x) { return 1.f / (1.f + expf(-x)); }
__device__ __forceinline__ float ldmix(const void* p, size_t i, int isbf) {
    return isbf ? bf2f(((const u16*)p)[i]) : ((const float*)p)[i];
}
// load input element (bf16 or fp32) -> fp16 bits
__device__ __forceinline__ u16 ld2h(const void* p, size_t i, int isbf) {
    return f2h(ldmix(p, i, isbf));
}

// split staging: load-to-regs / write-to-LDS (prefetch pipeline; 256-thread blocks)
__device__ __forceinline__ void ld128(half8 r[2], const u16* src, int row0, int ldK,
                                      int k0, int tid) {
    #pragma unroll
    for (int i = 0; i < 2; i++) {
        int v = tid + 256 * i;
        r[i] = *(const half8*)(src + (size_t)(row0 + (v >> 2)) * ldK + k0 + (v & 3) * 8);
    }
}
__device__ __forceinline__ void ld64(half8& r, const u16* src, int row0, int ldK,
                                     int k0, int tid) {
    r = *(const half8*)(src + (size_t)(row0 + (tid >> 2)) * ldK + k0 + (tid & 3) * 8);
}
// ---- stride-40 (80B) padded layout helpers (gemm_hyper, proven r7) ----
__device__ __forceinline__ void wr128(u16* lds, const half8 r[2], int tid) {
    #pragma unroll
    for (int i = 0; i < 2; i++) {
        int v = tid + 256 * i;
        *(half8*)&lds[(v >> 2) * 40 + (v & 3) * 8] = r[i];
    }
}
__device__ __forceinline__ void wr64(u16* lds, half8 r, int tid) {
    *(half8*)&lds[(tid >> 2) * 40 + (tid & 3) * 8] = r;
}
// ---- r8: unpadded 64B-row + XOR-swizzle layout (conflict-free reads AND writes) ----
// row stride 32 u16 = 4 bank-quads; phys slot = slot ^ ((row>>1)&3).
// Write octet: rows {R,R+1} -> quads {0-3} u {4-7} disjoint. Read octet (16 rows,
// same slot): q = 4r + g(r,s), g injective on even/odd rows separately. Uniform
// <=2-way at any phase granularity (2-way free, m136).
__device__ __forceinline__ void wrS128(u16* lds, const half8 r[2], int tid) {
    #pragma unroll
    for (int i = 0; i < 2; i++) {
        int v = tid + 256 * i;
        int ps = (v & 3) ^ ((v >> 3) & 3);
        *(half8*)&lds[(v >> 2) * 32 + ps * 8] = r[i];
    }
}
__device__ __forceinline__ void wrS64(u16* lds, half8 r, int tid) {
    int ps = (tid & 3) ^ ((tid >> 3) & 3);
    *(half8*)&lds[(tid >> 2) * 32 + ps * 8] = r;
}

// ---------------- dtype detection (1 = bf16, 0 = fp32) ----------------
__global__ void detect_dtype(const u16* __restrict__ raw, int* __restrict__ flag) {
    u16 u = raw[2 * threadIdx.x];
    int e = (u >> 7) & 0xFF;
    unsigned long long m = __ballot(e >= 100 && e <= 134);
    if (threadIdx.x == 0) *flag = (__popcll(m) >= 32) ? 1 : 0;
}

// ---------------- merged input conversion -> fp16: inputs->xh, main_h->mh, hyper_h->hh ----------------
__global__ void cvt_all(const void* __restrict__ xs, const void* __restrict__ ms,
                        const void* __restrict__ hs, u16* __restrict__ xh,
                        u16* __restrict__ mh, u16* __restrict__ hh, const int* __restrict__ flag) {
    int i = blockIdx.x * 256 + threadIdx.x;
    int isbf = *flag;
    const void* src; u16* dst; int t;
    if (i < 262144)      { src = xs; dst = xh; t = i; }
    else if (i < 524288) { src = ms; dst = mh; t = i - 262144; }
    else                 { src = hs; dst = hh; t = i - 524288; }  // < 65536
    #pragma unroll
    for (int j = 0; j < 8; j++)
        dst[(size_t)t * 8 + j] = ld2h(src, (size_t)t * 8 + j, isbf);
}

// ---------------- transpose(+convert->fp16): out[c*ostride+ocol+r]=in[r*C+c] ----------------
__global__ void transpose_cvt(const void* __restrict__ in, u16* __restrict__ out,
                              int R, int C, int ostride, int ocol,
                              const int* __restrict__ flag) {
    __shared__ u16 th[32][33];
    int isbf = *flag;
    int c0 = blockIdx.x * 32, r0 = blockIdx.y * 32;
    int tx = threadIdx.x, ty = threadIdx.y;  // block (32,8)
    #pragma unroll
    for (int i = 0; i < 32; i += 8)
        th[ty + i][tx] = ld2h(in, (size_t)(r0 + ty + i) * C + c0 + tx, isbf);
    __syncthreads();
    #pragma unroll
    for (int i = 0; i < 32; i += 8)
        out[(size_t)(c0 + ty + i) * ostride + ocol + r0 + tx] = th[tx][ty + i];
}

// z-dim variant: up to 3 (in,out) pairs with identical geometry
__global__ void transpose_z(const void* __restrict__ i0, const void* __restrict__ i1,
                            const void* __restrict__ i2, u16* __restrict__ o0,
                            u16* __restrict__ o1, u16* __restrict__ o2,
                            int R, int C, int ostride, const int* __restrict__ flag) {
    __shared__ u16 th[32][33];
    const void* in = (blockIdx.z == 0) ? i0 : (blockIdx.z == 1) ? i1 : i2;
    u16* out = (blockIdx.z == 0) ? o0 : (blockIdx.z == 1) ? o1 : o2;
    int isbf = *flag;
    int c0 = blockIdx.x * 32, r0 = blockIdx.y * 32;
    int tx = threadIdx.x, ty = threadIdx.y;
    #pragma unroll
    for (int i = 0; i < 32; i += 8)
        th[ty + i][tx] = ld2h(in, (size_t)(r0 + ty + i) * C + c0 + tx, isbf);
    __syncthreads();
    #pragma unroll
    for (int i = 0; i < 32; i += 8)
        out[(size_t)(c0 + ty + i) * ostride + r0 + tx] = th[tx][ty + i];
}

// ---------------- hyper GEMM (fp16): z = x@Wx + mh@Wm + hh@Wh ----------------
// r4: r3-proven register-prefetch + LBAR pipeline, unified step counter s in [0,72)
// across the 3 A-phases, and split-K x2 (blockIdx.z) -> 512 blocks = 2/CU overlap.
// Partial sums to zbuf halves; hyper_cell adds them. (r5 measured: dropped out of top-5.)
__device__ __forceinline__ void gh_load(half8 pA[2], half8& pB,
                                        const u16* xh, const u16* mh, const u16* hh,
                                        const u16* BT, int bm, int bn, int s, int tid) {
    const u16* Ap; int ldA, kA;
    if (s < 32)      { Ap = xh; ldA = 1024; kA = s * 32; }
    else if (s < 64) { Ap = mh; ldA = 1024; kA = (s - 32) * 32; }
    else             { Ap = hh; ldA = 256;  kA = (s - 64) * 32; }
    ld128(pA, Ap, bm, ldA, kA, tid);
    ld64(pB, BT, bn, 2304, s * 32, tid);
}

__global__ __launch_bounds__(256) void gemm_hyper(const u16* __restrict__ xh,
                                                  const u16* __restrict__ mh,
                                                  const u16* __restrict__ hh,
                                                  const u16* __restrict__ BT,
                                                  float* __restrict__ z) {
    __shared__ __align__(16) u16 sA[128 * 40];
    __shared__ __align__(16) u16 sB[64 * 40];
    int tid = threadIdx.x, lane = tid & 63, wave = tid >> 6;
    int wm = (wave & 1) * 64, wn = (wave >> 1) * 32;
    int bm = blockIdx.y * 128, bn = blockIdx.x * 64;
    int s0 = blockIdx.z * 36, s1 = s0 + 36;
    floatx4 acc[4][2] = {};
    int mr = lane & 15, kq = (lane >> 4) * 8;

    half8 pA[2]; half8 pB;
    gh_load(pA, pB, xh, mh, hh, BT, bm, bn, s0, tid);
    wr128(sA, pA, tid); wr64(sB, pB, tid);
    gh_load(pA, pB, xh, mh, hh, BT, bm, bn, s0 + 1, tid);
    LBAR();

    #pragma unroll 1
    for (int s = s0; s < s1; s++) {
        half8 a[4], b[2];
        #pragma unroll
        for (int t = 0; t < 4; t++) a[t] = *(const half8*)&sA[(wm + t * 16 + mr) * 40 + kq];
        #pragma unroll
        for (int t = 0; t < 2; t++) b[t] = *(const half8*)&sB[(wn + t * 16 + mr) * 40 + kq];
        #pragma unroll
        for (int tm = 0; tm < 4; tm++)
            #pragma unroll
            for (int tn = 0; tn < 2; tn++)
                acc[tm][tn] = MFMAH(a[tm], b[tn], acc[tm][tn], 0, 0, 0);
        LBAR();  // all waves done reading LDS -> safe to overwrite
        if (s < s1 - 1) {
            wr128(sA, pA, tid); wr64(sB, pB, tid);
            if (s < s1 - 2)
                gh_load(pA, pB, xh, mh, hh, BT, bm, bn, s + 2, tid);
            LBAR();  // writes visible
        }
    }

    float* zp = z + (size_t)blockIdx.z * 2048 * 1024;
    #pragma unroll
    for (int tm = 0; tm < 4; tm++)
        #pragma unroll
        for (int tn = 0; tn < 2; tn++) {
            int col = bn + wn + tn * 16 + (lane & 15);
            #pragma unroll
            for (int rr = 0; rr < 4; rr++) {
                int row = bm + wm + tm * 16 + (lane >> 4) * 4 + rr;
                zp[(size_t)row * 1024 + col] = acc[tm][tn][rr];
            }
        }
}

// ---------------- hyper LSTM cell (sums split-K halves); ho stored fp16 ----------------
__global__ void hyper_cell(const float* __restrict__ z, const void* __restrict__ hyper_c,
                           const void* __restrict__ hyper_bias, void* __restrict__ out,
                           u16* __restrict__ ho16, const int* __restrict__ flag) {
    int isbf = *flag;
    int t = blockIdx.x * 256 + threadIdx.x;
    int k = t & 255;
    const float* zr  = z + (size_t)(t >> 8) * 1024;
    const float* zr2 = zr + (size_t)2048 * 1024;
    float hi = zr[k]       + zr2[k]       + ldmix(hyper_bias, k, isbf);
    float hf = zr[k + 256] + zr2[k + 256] + ldmix(hyper_bias, k + 256, isbf);
    float hg = zr[k + 512] + zr2[k + 512] + ldmix(hyper_bias, k + 512, isbf);
    float ho = zr[k + 768] + zr2[k + 768] + ldmix(hyper_bias, k + 768, isbf);
    float c  = ldmix(hyper_c, t, isbf);
    float cn = sigf(hf) * c + sigf(hi) * tanhf(hg);
    float hout = sigf(ho) * tanhf(cn);
    ho16[t] = f2h(hout);
    if (isbf) {
        ((u16*)out)[O_HO + t] = f2bf(hout);
        ((u16*)out)[O_HC + t] = f2bf(cn);
    } else {
        ((float*)out)[O_HO + t] = hout;
        ((float*)out)[O_HC + t] = cn;
    }
}

// ---------------- fused gates GEMM (fp16, 5 acc sets) -> gates_pre fp16 ----------------
// block 128M x 64N, waves 2(M)x2(N), wave tile 64x32 PER SET.
// r7: LDS double-buffer, 1 LBAR/step, reg-prefetch dist 1 (87.8us, MfmaUtil 22.7%).
// r8: bank-conflict fix — stride-40 layout had 1.52e7 conflict-cycles (~28% of
// runtime/CU). New layout: unpadded 32-u16 rows + XOR slot swizzle (see wrS64).
// Also shrinks LDS 61440->49152 B -> 3 blocks/CU resident.
// Buffer layout (u16): ph1 A1@0[128x32] A2@4096 B1@8192[64x32] B2@10240;
//                      ph2 A@0 B3@4096 B1@8192 B2@10240.
__global__ __launch_bounds__(256, 2) void mega_fused(
    const u16* __restrict__ xh, const u16* __restrict__ mh, const u16* __restrict__ ho16,
    const u16* __restrict__ kT, const u16* __restrict__ rkT,
    const u16* __restrict__ dxT, const u16* __restrict__ dhT, const u16* __restrict__ dbT,
    const void* __restrict__ bias, const void* __restrict__ dx_b,
    const void* __restrict__ dh_b, const void* __restrict__ db_b,
    u16* __restrict__ gp, const int* __restrict__ flag) {
    __shared__ __align__(16) u16 S[2][12288];
    int isbf = *flag;
    int tid = threadIdx.x, lane = tid & 63, wave = tid >> 6;
    int wm = (wave & 1) * 64, wn = (wave >> 1) * 32;
    int bm = blockIdx.y * 128, bn = blockIdx.x * 64;
    floatx4 apx[4][2] = {}, aph[4][2] = {}, adx[4][2] = {}, adh[4][2] = {}, adb[4][2] = {};
    int mr = lane & 15;
    // swizzled k-chunk offset: phys slot = (lane>>4) ^ ((row>>1)&3); row>>1&3 == mr>>1&3
    // (wm/wn/t*16 are multiples of 16 -> contribute 0). Same involution as wrS*.
    int kqs = (((lane >> 4) ^ ((mr >> 1) & 3))) * 8;

    half8 nA1[2], nA2[2], nB1, nB2, nB3;

    // ---- prologue: tile0 -> regs -> buf0 ; tile1 -> regs ; barrier ----
    ld128(nA1, xh,  bm, 1024, 0, tid);
    ld128(nA2, mh,  bm, 1024, 0, tid);
    ld64(nB1, kT,  bn, 1024, 0, tid);
    ld64(nB2, rkT, bn, 1024, 0, tid);
    wrS128(S[0], nA1, tid); wrS128(S[0] + 4096, nA2, tid);
    wrS64(S[0] + 8192, nB1, tid); wrS64(S[0] + 10240, nB2, tid);
    ld128(nA1, xh,  bm, 1024, 32, tid);
    ld128(nA2, mh,  bm, 1024, 32, tid);
    ld64(nB1, kT,  bn, 1024, 32, tid);
    ld64(nB2, rkT, bn, 1024, 32, tid);
    LBAR();

    // ---- phase 1: px = x@kT, ph = mh@rkT  (K=1024), 1 barrier/step ----
    #pragma unroll 1
    for (int k0 = 0; k0 < 1024; k0 += 32) {
        int p = (k0 >> 5) & 1;
        const u16* C = S[p];
        u16* N = S[p ^ 1];
        half8 ax[4], am[4], bk[2], br[2];
        #pragma unroll
        for (int t = 0; t < 4; t++) {
            int ra = (wm + t * 16 + mr) * 32 + kqs;
            ax[t] = *(const half8*)&C[ra];
            am[t] = *(const half8*)&C[4096 + ra];
        }
        #pragma unroll
        for (int t = 0; t < 2; t++) {
            int rb = (wn + t * 16 + mr) * 32 + kqs;
            bk[t] = *(const half8*)&C[8192 + rb];
            br[t] = *(const half8*)&C[10240 + rb];
        }
        // stage next tile (in regs) into the other buffer — overlaps MFMA below
        if (k0 < 992) {
            wrS128(N, nA1, tid); wrS128(N + 4096, nA2, tid);
            wrS64(N + 8192, nB1, tid); wrS64(N + 10240, nB2, tid);
        } else {
            // last ph1 step: stage PHASE-2 tile0 (loaded at k0==960), phase2 layout
            wrS128(N, nA1, tid);
            wrS64(N + 8192, nB1, tid); wrS64(N + 10240, nB2, tid); wrS64(N + 4096, nB3, tid);
        }
        // prefetch tile k0+64 into regs
        if (k0 < 960) {
            ld128(nA1, xh,  bm, 1024, k0 + 64, tid);
            ld128(nA2, mh,  bm, 1024, k0 + 64, tid);
            ld64(nB1, kT,  bn, 1024, k0 + 64, tid);
            ld64(nB2, rkT, bn, 1024, k0 + 64, tid);
        } else if (k0 == 960) {
            ld128(nA1, ho16, bm, 256, 0, tid);
            ld64(nB1, dxT, bn, 256, 0, tid);
            ld64(nB2, dhT, bn, 256, 0, tid);
            ld64(nB3, dbT, bn, 256, 0, tid);
        } else {  // k0 == 992: phase-2 tile1
            ld128(nA1, ho16, bm, 256, 32, tid);
            ld64(nB1, dxT, bn, 256, 32, tid);
            ld64(nB2, dhT, bn, 256, 32, tid);
            ld64(nB3, dbT, bn, 256, 32, tid);
        }
        #pragma unroll
        for (int tm = 0; tm < 4; tm++)
            #pragma unroll
            for (int tn = 0; tn < 2; tn++) {
                apx[tm][tn] = MFMAH(ax[tm], bk[tn], apx[tm][tn], 0, 0, 0);
                aph[tm][tn] = MFMAH(am[tm], br[tn], aph[tm][tn], 0, 0, 0);
            }
        LBAR();
    }

    // ---- phase 2: d_* = ho @ {dxT,dhT,dbT}  (K=256); A shared by 3 sets ----
    #pragma unroll 1
    for (int k0 = 0; k0 < 256; k0 += 32) {
        int p = (k0 >> 5) & 1;
        const u16* C = S[p];
        u16* N = S[p ^ 1];
        half8 a[4], bx[2], bh[2], bb[2];
        #pragma unroll
        for (int t = 0; t < 4; t++) {
            int ra = (wm + t * 16 + mr) * 32 + kqs;
            a[t] = *(const half8*)&C[ra];
        }
        #pragma unroll
        for (int t = 0; t < 2; t++) {
            int rb = (wn + t * 16 + mr) * 32 + kqs;
            bx[t] = *(const half8*)&C[8192 + rb];
            bh[t] = *(const half8*)&C[10240 + rb];
            bb[t] = *(const half8*)&C[4096 + rb];
        }
        if (k0 < 224) {
            wrS128(N, nA1, tid);
            wrS64(N + 8192, nB1, tid); wrS64(N + 10240, nB2, tid); wrS64(N + 4096, nB3, tid);
        }
        if (k0 < 192) {
            ld128(nA1, ho16, bm, 256, k0 + 64, tid);
            ld64(nB1, dxT, bn, 256, k0 + 64, tid);
            ld64(nB2, dhT, bn, 256, k0 + 64, tid);
            ld64(nB3, dbT, bn, 256, k0 + 64, tid);
        }
        #pragma unroll
        for (int tm = 0; tm < 4; tm++)
            #pragma unroll
            for (int tn = 0; tn < 2; tn++) {
                adx[tm][tn] = MFMAH(a[tm], bx[tn], adx[tm][tn], 0, 0, 0);
                adh[tm][tn] = MFMAH(a[tm], bh[tn], adh[tm][tn], 0, 0, 0);
                adb[tm][tn] = MFMAH(a[tm], bb[tn], adb[tm][tn], 0, 0, 0);
            }
        LBAR();
    }

    // epilogue: g = (adx+dxb)*(apx+bias) + (adh+dhb)*aph + (adb+dbb), stored fp16
    #pragma unroll
    for (int tn = 0; tn < 2; tn++) {
        int col = bn + wn + tn * 16 + (lane & 15);
        float bv  = ldmix(bias, col, isbf);
        float dxb = ldmix(dx_b, col, isbf);
        float dhb = ldmix(dh_b, col, isbf);
        float dbb = ldmix(db_b, col, isbf);
        #pragma unroll
        for (int tm = 0; tm < 4; tm++) {
            #pragma unroll
            for (int rr = 0; rr < 4; rr++) {
                int row = bm + wm + tm * 16 + (lane >> 4) * 4 + rr;
                float px = apx[tm][tn][rr] + bv;
                float ph = aph[tm][tn][rr];
                float dx = adx[tm][tn][rr] + dxb;
                float dh = adh[tm][tn][rr] + dhb;
                float db = adb[tm][tn][rr] + dbb;
                gp[(size_t)row * 4096 + col] = f2h(dx * px + dh * ph + db);
            }
        }
    }
}

// ---------------- LN(4096) -> gates -> c_new -> LN(1024) -> h_new ----------------
__device__ __forceinline__ void block_reduce2(float& a, float& b, float* red) {
    #pragma unroll
    for (int o = 32; o > 0; o >>= 1) {
        a += __shfl_down(a, o, 64);
        b += __shfl_down(b, o, 64);
    }
    int lane = threadIdx.x & 63, w = threadIdx.x >> 6;
    if (lane == 0) { red[w] = a; red[4 + w] = b; }
    __syncthreads();
    a = red[0] + red[1] + red[2] + red[3];
    b = red[4] + red[5] + red[6] + red[7];
    __syncthreads();
}

__global__ __launch_bounds__(256) void ln_main(const u16* __restrict__ gp,
                                               const void* __restrict__ main_c,
                                               void* __restrict__ out,
                                               const int* __restrict__ flag) {
    __shared__ float sPre[4096];
    __shared__ float sC[1024];
    __shared__ float red[8];
    int isbf = *flag;
    int b = blockIdx.x, tid = threadIdx.x;
    const u16* g = gp + (size_t)b * 4096;
    float s = 0.f, q = 0.f;
    for (int j0 = tid * 8; j0 < 4096; j0 += 2048) {
        half8 v = *(const half8*)(g + j0);
        #pragma unroll
        for (int e = 0; e < 8; e++) {
            float f = (float)v[e];
            sPre[j0 + e] = f; s += f; q += f * f;
        }
    }
    block_reduce2(s, q, red);
    float mean = s * (1.f / 4096.f);
    float var = q * (1.f / 4096.f) - mean * mean;
    float rs = rsqrtf(var + 1e-3f);
    float s2 = 0.f, q2 = 0.f;
    for (int u = tid; u < 1024; u += 256) {
        float gi = (sPre[u] - mean) * rs;
        float gf = (sPre[u + 1024] - mean) * rs;
        float gg = (sPre[u + 2048] - mean) * rs;
        float c = ldmix(main_c, (size_t)b * 1024 + u, isbf);
        float cn = sigf(gf) * c + sigf(gi) * tanhf(gg);
        sC[u] = cn;
        if (isbf) ((u16*)out)[O_C + (size_t)b * 1024 + u] = f2bf(cn);
        else      ((float*)out)[O_C + (size_t)b * 1024 + u] = cn;
        s2 += cn; q2 += cn * cn;
    }
    block_reduce2(s2, q2, red);
    float m2 = s2 * (1.f / 1024.f);
    float v2 = q2 * (1.f / 1024.f) - m2 * m2;
    float rs2 = rsqrtf(v2 + 1e-3f);
    for (int u = tid; u < 1024; u += 256) {
        float go = (sPre[u + 3072] - mean) * rs;
        float hn = sigf(go) * tanhf((sC[u] - m2) * rs2);
        if (isbf) ((u16*)out)[O_H + (size_t)b * 1024 + u] = f2bf(hn);
        else      ((float*)out)[O_H + (size_t)b * 1024 + u] = hn;
    }
}

// ---------------- launcher ----------------
extern "C" void kernel_launch(void* const* d_in, const int* in_sizes, int n_in,
                              void* d_out, int out_size, void* d_ws, size_t ws_size,
                              hipStream_t stream) {
    (void)in_sizes; (void)n_in; (void)out_size; (void)ws_size;
    const void* inputs   = d_in[0];
    const void* main_h   = d_in[1];
    const void* main_c   = d_in[2];
    const void* hyper_h  = d_in[3];
    const void* hyper_c  = d_in[4];
    const void* kernel_w = d_in[5];
    const void* rec_w    = d_in[6];
    const void* bias     = d_in[7];
    const void* hyper_k  = d_in[8];
    const void* hyper_rk = d_in[9];
    const void* hyper_b  = d_in[10];
    const void* dx_w = d_in[11];
    const void* dx_b = d_in[12];
    const void* dh_w = d_in[13];
    const void* dh_b = d_in[14];
    const void* db_w = d_in[15];
    const void* db_b = d_in[16];
    char* ws = (char*)d_ws;
    const size_t MB = 1024 * 1024;

    // workspace layout, NO overlays (ws >= 100 MB proven in r6/r7)
    int* flag = (int*)ws;
    size_t off = 256;
    u16* xh  = (u16*)(ws + off); off += 4 * MB;            // [2048,1024] fp16
    u16* mh  = (u16*)(ws + off); off += 4 * MB;            // [2048,1024] fp16
    u16* hh  = (u16*)(ws + off); off += 1 * MB;            // [2048,256]  fp16
    u16* ho  = (u16*)(ws + off); off += 1 * MB;            // [2048,256]  fp16
    u16* kT  = (u16*)(ws + off); off += 8 * MB;            // [4096,1024] fp16
    u16* rkT = (u16*)(ws + off); off += 8 * MB;            // [4096,1024] fp16
    u16* dxT = (u16*)(ws + off); off += 2 * MB;            // [4096,256]  fp16
    u16* dhT = (u16*)(ws + off); off += 2 * MB;
    u16* dbT = (u16*)(ws + off); off += 2 * MB;
    u16* BTh = (u16*)(ws + off); off += (size_t)1024 * 2304 * 2;  // 4.5 MB
    float* zbuf = (float*)(ws + off); off += 16 * MB;      // [2, 2048,1024] fp32 (split-K halves)
    u16* gp    = (u16*)(ws + off); off += 16 * MB;         // [2048,4096] fp16

    detect_dtype<<<1, 64, 0, stream>>>((const u16*)inputs, flag);
    cvt_all<<<2304, 256, 0, stream>>>(inputs, main_h, hyper_h, xh, mh, hh, flag);

    dim3 tblk(32, 8);
    transpose_cvt<<<dim3(32, 64), tblk, 0, stream>>>(hyper_k, BTh, 2048, 1024, 2304, 0, flag);
    transpose_cvt<<<dim3(32, 8),  tblk, 0, stream>>>(hyper_rk, BTh, 256, 1024, 2304, 2048, flag);
    transpose_z<<<dim3(128, 32, 2), tblk, 0, stream>>>(kernel_w, rec_w, rec_w,
                                                       kT, rkT, rkT, 1024, 4096, 1024, flag);
    transpose_z<<<dim3(128, 8, 3), tblk, 0, stream>>>(dx_w, dh_w, db_w,
                                                      dxT, dhT, dbT, 256, 4096, 256, flag);

    gemm_hyper<<<dim3(16, 16, 2), 256, 0, stream>>>(xh, mh, hh, BTh, zbuf);
    hyper_cell<<<2048, 256, 0, stream>>>(zbuf, hyper_c, hyper_b, d_out, ho, flag);
    mega_fused<<<dim3(64, 16), 256, 0, stream>>>(xh, mh, ho, kT, rkT, dxT, dhT, dbT,
                                                 bias, dx_b, dh_b, db_b, gp, flag);
    ln_main<<<2048, 256, 0, stream>>>(gp, main_c, d_out, flag);
}

// Round 9
// 269.628 us; speedup vs baseline: 1.3558x; 1.0705x over previous
//
#include <hip/hip_runtime.h>
#include <cstdint>

typedef unsigned short u16;
typedef _Float16 half8 __attribute__((ext_vector_type(8)));
typedef float floatx4 __attribute__((ext_vector_type(4)));
typedef unsigned short ushort8v __attribute__((ext_vector_type(8)));
typedef float float4v __attribute__((ext_vector_type(4)));

#define BB 2048
#define UU 1024
#define HUx 256
#define O_H  0
#define O_C  (BB*UU)
#define O_HO (2*BB*UU)
#define O_HC (2*BB*UU + BB*HUx)
#define MFMAH __builtin_amdgcn_mfma_f32_16x16x32_f16

// raw barrier: ds-write visibility (lgkmcnt) without the __syncthreads vmcnt(0) drain,
// so prefetched global loads stay in flight across barriers (T3/T4 mechanism).
// sched_barrier(0) pins ordering (rule #18: hipcc can hoist reg-only ops past asm waitcnt).
#define LBAR() do { \
    asm volatile("s_waitcnt lgkmcnt(0)\n\ts_barrier" ::: "memory"); \
    __builtin_amdgcn_sched_barrier(0); \
} while (0)

__device__ __forceinline__ float bf2f(u16 u) {
    union { uint32_t i; float f; } v; v.i = ((uint32_t)u) << 16; return v.f;
}
__device__ __forceinline__ u16 f2bf(float f) {
    union { float f; uint32_t i; } v; v.f = f;
    uint32_t r = v.i + 0x7fffu + ((v.i >> 16) & 1u);
    return (u16)(r >> 16);
}
__device__ __forceinline__ u16 f2h(float f) {
    _Float16 h = (_Float16)f; u16 u; __builtin_memcpy(&u, &h, 2); return u;
}
__device__ __forceinline__ float sigf(float x) { return 1.f / (1.f + expf(-x)); }
__device__ __forceinline__ float ldmix(const void* p, size_t i, int isbf) {
    return isbf ? bf2f(((const u16*)p)[i]) : ((const float*)p)[i];
}
// load input element (bf16 or fp32) -> fp16 bits
__device__ __forceinline__ u16 ld2h(const void* p, size_t i, int isbf) {
    return f2h(ldmix(p, i, isbf));
}

// split staging: load-to-regs / write-to-LDS (prefetch pipeline; 256-thread blocks)
__device__ __forceinline__ void ld128(half8 r[2], const u16* src, int row0, int ldK,
                                      int k0, int tid) {
    #pragma unroll
    for (int i = 0; i < 2; i++) {
        int v = tid + 256 * i;
        r[i] = *(const half8*)(src + (size_t)(row0 + (v >> 2)) * ldK + k0 + (v & 3) * 8);
    }
}
__device__ __forceinline__ void ld64(half8& r, const u16* src, int row0, int ldK,
                                     int k0, int tid) {
    r = *(const half8*)(src + (size_t)(row0 + (tid >> 2)) * ldK + k0 + (tid & 3) * 8);
}
// ---- stride-40 (80B) padded layout helpers (gemm_hyper, proven r7) ----
__device__ __forceinline__ void wr128(u16* lds, const half8 r[2], int tid) {
    #pragma unroll
    for (int i = 0; i < 2; i++) {
        int v = tid + 256 * i;
        *(half8*)&lds[(v >> 2) * 40 + (v & 3) * 8] = r[i];
    }
}
__device__ __forceinline__ void wr64(u16* lds, half8 r, int tid) {
    *(half8*)&lds[(tid >> 2) * 40 + (tid & 3) * 8] = r;
}
// ---- r8: unpadded 64B-row + XOR-swizzle layout (conflict-free reads AND writes) ----
// row stride 32 u16 = 4 bank-quads; phys slot = slot ^ ((row>>1)&3).
// PROVEN r8: SQ_LDS_BANK_CONFLICT 1.52e7 -> 0.
__device__ __forceinline__ void wrS128(u16* lds, const half8 r[2], int tid) {
    #pragma unroll
    for (int i = 0; i < 2; i++) {
        int v = tid + 256 * i;
        int ps = (v & 3) ^ ((v >> 3) & 3);
        *(half8*)&lds[(v >> 2) * 32 + ps * 8] = r[i];
    }
}
__device__ __forceinline__ void wrS64(u16* lds, half8 r, int tid) {
    int ps = (tid & 3) ^ ((tid >> 3) & 3);
    *(half8*)&lds[(tid >> 2) * 32 + ps * 8] = r;
}

// ---------------- merged preprocessing: dtype-detect + cvt + all transposes ----------------
// r9: was 6 launches (detect, cvt_all, transpose_cvt x2, transpose_z x2) totaling a
// large share of the ~208us non-mega time (launch ramps/tails + serial gaps).
// One 15872-block kernel; role by blockIdx range. Each block computes isbf LOCALLY
// (wave ballot over first 64 exponents of `inputs`) -> no flag dependency; block 0
// publishes the flag for downstream kernels (hyper_cell / mega / ln_main).
__device__ __forceinline__ int detect_local(const u16* raw) {
    int lane = threadIdx.x & 63;
    u16 u = raw[2 * lane];
    int e = (u >> 7) & 0xFF;
    unsigned long long m = __ballot(e >= 100 && e <= 134);
    return (__popcll(m) >= 32) ? 1 : 0;
}

__device__ __forceinline__ void transpose_tile(const void* in, u16* out, int C,
                                               int ostride, int ocol, int r0, int c0,
                                               int isbf, u16 th[32][33]) {
    int tid = threadIdx.x;
    int tx = tid & 31, ty = tid >> 5;  // 256 threads = (32,8)
    #pragma unroll
    for (int i = 0; i < 32; i += 8)
        th[ty + i][tx] = ld2h(in, (size_t)(r0 + ty + i) * C + c0 + tx, isbf);
    __syncthreads();
    #pragma unroll
    for (int i = 0; i < 32; i += 8)
        out[(size_t)(c0 + ty + i) * ostride + ocol + r0 + tx] = th[tx][ty + i];
}

__global__ __launch_bounds__(256) void prep_all(
    const void* __restrict__ xs, const void* __restrict__ ms, const void* __restrict__ hs,
    const void* __restrict__ hyper_k, const void* __restrict__ hyper_rk,
    const void* __restrict__ kernel_w, const void* __restrict__ rec_w,
    const void* __restrict__ dx_w, const void* __restrict__ dh_w, const void* __restrict__ db_w,
    u16* __restrict__ xh, u16* __restrict__ mh, u16* __restrict__ hh,
    u16* __restrict__ BTh, u16* __restrict__ kT, u16* __restrict__ rkT,
    u16* __restrict__ dxT, u16* __restrict__ dhT, u16* __restrict__ dbT,
    int* __restrict__ flag) {
    __shared__ u16 th[32][33];
    int bid = blockIdx.x, tid = threadIdx.x;
    int isbf = detect_local((const u16*)xs);
    if (bid == 0 && tid == 0) *flag = isbf;

    if (bid < 2304) {
        // ---- cvt role: vectorized loads + single 16B store per thread ----
        int i = bid * 256 + tid;
        const void* src; u16* dst; int t;
        if (i < 262144)      { src = xs; dst = xh; t = i; }
        else if (i < 524288) { src = ms; dst = mh; t = i - 262144; }
        else                 { src = hs; dst = hh; t = i - 524288; }  // < 589824
        half8 o;
        if (isbf) {
            ushort8v v = *(const ushort8v*)((const u16*)src + (size_t)t * 8);
            #pragma unroll
            for (int j = 0; j < 8; j++) o[j] = (_Float16)bf2f(v[j]);
        } else {
            float4v a = *(const float4v*)((const float*)src + (size_t)t * 8);
            float4v b = *(const float4v*)((const float*)src + (size_t)t * 8 + 4);
            #pragma unroll
            for (int j = 0; j < 4; j++) { o[j] = (_Float16)a[j]; o[j + 4] = (_Float16)b[j]; }
        }
        *(half8*)(dst + (size_t)t * 8) = o;
    } else if (bid < 4352) {
        // ---- hyper_k transpose: R=2048, C=1024 -> BTh[.,2304] ocol 0 ----
        int u = bid - 2304;
        transpose_tile(hyper_k, BTh, 1024, 2304, 0, (u >> 5) * 32, (u & 31) * 32, isbf, th);
    } else if (bid < 4608) {
        // ---- hyper_rk transpose: R=256, C=1024 -> BTh ocol 2048 ----
        int u = bid - 4352;
        transpose_tile(hyper_rk, BTh, 1024, 2304, 2048, (u >> 5) * 32, (u & 31) * 32, isbf, th);
    } else if (bid < 12800) {
        // ---- kernel_w / rec_w transpose: R=1024, C=4096 -> kT / rkT ----
        int u = bid - 4608;
        int z = u >> 12;              // /4096
        int r = u & 4095;
        const void* in = z ? rec_w : kernel_w;
        u16* out = z ? rkT : kT;
        transpose_tile(in, out, 4096, 1024, 0, (r >> 7) * 32, (r & 127) * 32, isbf, th);
    } else {
        // ---- dx/dh/db transpose: R=256, C=4096 -> dxT/dhT/dbT ----
        int u = bid - 12800;
        int z = u >> 10;              // /1024
        int r = u & 1023;
        const void* in = (z == 0) ? dx_w : (z == 1) ? dh_w : db_w;
        u16* out = (z == 0) ? dxT : (z == 1) ? dhT : dbT;
        transpose_tile(in, out, 4096, 256, 0, (r >> 7) * 32, (r & 127) * 32, isbf, th);
    }
}

// ---------------- hyper GEMM (fp16): z = x@Wx + mh@Wm + hh@Wh ----------------
// r4: r3-proven register-prefetch + LBAR pipeline, unified step counter s in [0,72)
// across the 3 A-phases, and split-K x2 (blockIdx.z) -> 512 blocks = 2/CU overlap.
// Partial sums to zbuf halves; hyper_cell adds them. (r5 measured: dropped out of top-5.)
__device__ __forceinline__ void gh_load(half8 pA[2], half8& pB,
                                        const u16* xh, const u16* mh, const u16* hh,
                                        const u16* BT, int bm, int bn, int s, int tid) {
    const u16* Ap; int ldA, kA;
    if (s < 32)      { Ap = xh; ldA = 1024; kA = s * 32; }
    else if (s < 64) { Ap = mh; ldA = 1024; kA = (s - 32) * 32; }
    else             { Ap = hh; ldA = 256;  kA = (s - 64) * 32; }
    ld128(pA, Ap, bm, ldA, kA, tid);
    ld64(pB, BT, bn, 2304, s * 32, tid);
}

__global__ __launch_bounds__(256) void gemm_hyper(const u16* __restrict__ xh,
                                                  const u16* __restrict__ mh,
                                                  const u16* __restrict__ hh,
                                                  const u16* __restrict__ BT,
                                                  float* __restrict__ z) {
    __shared__ __align__(16) u16 sA[128 * 40];
    __shared__ __align__(16) u16 sB[64 * 40];
    int tid = threadIdx.x, lane = tid & 63, wave = tid >> 6;
    int wm = (wave & 1) * 64, wn = (wave >> 1) * 32;
    int bm = blockIdx.y * 128, bn = blockIdx.x * 64;
    int s0 = blockIdx.z * 36, s1 = s0 + 36;
    floatx4 acc[4][2] = {};
    int mr = lane & 15, kq = (lane >> 4) * 8;

    half8 pA[2]; half8 pB;
    gh_load(pA, pB, xh, mh, hh, BT, bm, bn, s0, tid);
    wr128(sA, pA, tid); wr64(sB, pB, tid);
    gh_load(pA, pB, xh, mh, hh, BT, bm, bn, s0 + 1, tid);
    LBAR();

    #pragma unroll 1
    for (int s = s0; s < s1; s++) {
        half8 a[4], b[2];
        #pragma unroll
        for (int t = 0; t < 4; t++) a[t] = *(const half8*)&sA[(wm + t * 16 + mr) * 40 + kq];
        #pragma unroll
        for (int t = 0; t < 2; t++) b[t] = *(const half8*)&sB[(wn + t * 16 + mr) * 40 + kq];
        #pragma unroll
        for (int tm = 0; tm < 4; tm++)
            #pragma unroll
            for (int tn = 0; tn < 2; tn++)
                acc[tm][tn] = MFMAH(a[tm], b[tn], acc[tm][tn], 0, 0, 0);
        LBAR();  // all waves done reading LDS -> safe to overwrite
        if (s < s1 - 1) {
            wr128(sA, pA, tid); wr64(sB, pB, tid);
            if (s < s1 - 2)
                gh_load(pA, pB, xh, mh, hh, BT, bm, bn, s + 2, tid);
            LBAR();  // writes visible
        }
    }

    float* zp = z + (size_t)blockIdx.z * 2048 * 1024;
    #pragma unroll
    for (int tm = 0; tm < 4; tm++)
        #pragma unroll
        for (int tn = 0; tn < 2; tn++) {
            int col = bn + wn + tn * 16 + (lane & 15);
            #pragma unroll
            for (int rr = 0; rr < 4; rr++) {
                int row = bm + wm + tm * 16 + (lane >> 4) * 4 + rr;
                zp[(size_t)row * 1024 + col] = acc[tm][tn][rr];
            }
        }
}

// ---------------- hyper LSTM cell (sums split-K halves); ho stored fp16 ----------------
__global__ void hyper_cell(const float* __restrict__ z, const void* __restrict__ hyper_c,
                           const void* __restrict__ hyper_bias, void* __restrict__ out,
                           u16* __restrict__ ho16, const int* __restrict__ flag) {
    int isbf = *flag;
    int t = blockIdx.x * 256 + threadIdx.x;
    int k = t & 255;
    const float* zr  = z + (size_t)(t >> 8) * 1024;
    const float* zr2 = zr + (size_t)2048 * 1024;
    float hi = zr[k]       + zr2[k]       + ldmix(hyper_bias, k, isbf);
    float hf = zr[k + 256] + zr2[k + 256] + ldmix(hyper_bias, k + 256, isbf);
    float hg = zr[k + 512] + zr2[k + 512] + ldmix(hyper_bias, k + 512, isbf);
    float ho = zr[k + 768] + zr2[k + 768] + ldmix(hyper_bias, k + 768, isbf);
    float c  = ldmix(hyper_c, t, isbf);
    float cn = sigf(hf) * c + sigf(hi) * tanhf(hg);
    float hout = sigf(ho) * tanhf(cn);
    ho16[t] = f2h(hout);
    if (isbf) {
        ((u16*)out)[O_HO + t] = f2bf(hout);
        ((u16*)out)[O_HC + t] = f2bf(cn);
    } else {
        ((float*)out)[O_HO + t] = hout;
        ((float*)out)[O_HC + t] = cn;
    }
}

// ---------------- fused gates GEMM (fp16, 5 acc sets) -> gates_pre fp16 ----------------
// block 128M x 64N, waves 2(M)x2(N), wave tile 64x32 PER SET.
// r7: LDS double-buffer, 1 LBAR/step, reg-prefetch dist 1 (87.8us).
// r8: XOR-swizzle layout -> bank conflicts 1.52e7 -> 0; 80.3us, MfmaUtil 24.8%.
// UNCHANGED in r9.
__global__ __launch_bounds__(256, 2) void mega_fused(
    const u16* __restrict__ xh, const u16* __restrict__ mh, const u16* __restrict__ ho16,
    const u16* __restrict__ kT, const u16* __restrict__ rkT,
    const u16* __restrict__ dxT, const u16* __restrict__ dhT, const u16* __restrict__ dbT,
    const void* __restrict__ bias, const void* __restrict__ dx_b,
    const void* __restrict__ dh_b, const void* __restrict__ db_b,
    u16* __restrict__ gp, const int* __restrict__ flag) {
    __shared__ __align__(16) u16 S[2][12288];
    int isbf = *flag;
    int tid = threadIdx.x, lane = tid & 63, wave = tid >> 6;
    int wm = (wave & 1) * 64, wn = (wave >> 1) * 32;
    int bm = blockIdx.y * 128, bn = blockIdx.x * 64;
    floatx4 apx[4][2] = {}, aph[4][2] = {}, adx[4][2] = {}, adh[4][2] = {}, adb[4][2] = {};
    int mr = lane & 15;
    // swizzled k-chunk offset: phys slot = (lane>>4) ^ ((row>>1)&3); row>>1&3 == mr>>1&3
    // (wm/wn/t*16 are multiples of 16 -> contribute 0). Same involution as wrS*.
    int kqs = (((lane >> 4) ^ ((mr >> 1) & 3))) * 8;

    half8 nA1[2], nA2[2], nB1, nB2, nB3;

    // ---- prologue: tile0 -> regs -> buf0 ; tile1 -> regs ; barrier ----
    ld128(nA1, xh,  bm, 1024, 0, tid);
    ld128(nA2, mh,  bm, 1024, 0, tid);
    ld64(nB1, kT,  bn, 1024, 0, tid);
    ld64(nB2, rkT, bn, 1024, 0, tid);
    wrS128(S[0], nA1, tid); wrS128(S[0] + 4096, nA2, tid);
    wrS64(S[0] + 8192, nB1, tid); wrS64(S[0] + 10240, nB2, tid);
    ld128(nA1, xh,  bm, 1024, 32, tid);
    ld128(nA2, mh,  bm, 1024, 32, tid);
    ld64(nB1, kT,  bn, 1024, 32, tid);
    ld64(nB2, rkT, bn, 1024, 32, tid);
    LBAR();

    // ---- phase 1: px = x@kT, ph = mh@rkT  (K=1024), 1 barrier/step ----
    #pragma unroll 1
    for (int k0 = 0; k0 < 1024; k0 += 32) {
        int p = (k0 >> 5) & 1;
        const u16* C = S[p];
        u16* N = S[p ^ 1];
        half8 ax[4], am[4], bk[2], br[2];
        #pragma unroll
        for (int t = 0; t < 4; t++) {
            int ra = (wm + t * 16 + mr) * 32 + kqs;
            ax[t] = *(const half8*)&C[ra];
            am[t] = *(const half8*)&C[4096 + ra];
        }
        #pragma unroll
        for (int t = 0; t < 2; t++) {
            int rb = (wn + t * 16 + mr) * 32 + kqs;
            bk[t] = *(const half8*)&C[8192 + rb];
            br[t] = *(const half8*)&C[10240 + rb];
        }
        // stage next tile (in regs) into the other buffer — overlaps MFMA below
        if (k0 < 992) {
            wrS128(N, nA1, tid); wrS128(N + 4096, nA2, tid);
            wrS64(N + 8192, nB1, tid); wrS64(N + 10240, nB2, tid);
        } else {
            // last ph1 step: stage PHASE-2 tile0 (loaded at k0==960), phase2 layout
            wrS128(N, nA1, tid);
            wrS64(N + 8192, nB1, tid); wrS64(N + 10240, nB2, tid); wrS64(N + 4096, nB3, tid);
        }
        // prefetch tile k0+64 into regs
        if (k0 < 960) {
            ld128(nA1, xh,  bm, 1024, k0 + 64, tid);
            ld128(nA2, mh,  bm, 1024, k0 + 64, tid);
            ld64(nB1, kT,  bn, 1024, k0 + 64, tid);
            ld64(nB2, rkT, bn, 1024, k0 + 64, tid);
        } else if (k0 == 960) {
            ld128(nA1, ho16, bm, 256, 0, tid);
            ld64(nB1, dxT, bn, 256, 0, tid);
            ld64(nB2, dhT, bn, 256, 0, tid);
            ld64(nB3, dbT, bn, 256, 0, tid);
        } else {  // k0 == 992: phase-2 tile1
            ld128(nA1, ho16, bm, 256, 32, tid);
            ld64(nB1, dxT, bn, 256, 32, tid);
            ld64(nB2, dhT, bn, 256, 32, tid);
            ld64(nB3, dbT, bn, 256, 32, tid);
        }
        #pragma unroll
        for (int tm = 0; tm < 4; tm++)
            #pragma unroll
            for (int tn = 0; tn < 2; tn++) {
                apx[tm][tn] = MFMAH(ax[tm], bk[tn], apx[tm][tn], 0, 0, 0);
                aph[tm][tn] = MFMAH(am[tm], br[tn], aph[tm][tn], 0, 0, 0);
            }
        LBAR();
    }

    // ---- phase 2: d_* = ho @ {dxT,dhT,dbT}  (K=256); A shared by 3 sets ----
    #pragma unroll 1
    for (int k0 = 0; k0 < 256; k0 += 32) {
        int p = (k0 >> 5) & 1;
        const u16* C = S[p];
        u16* N = S[p ^ 1];
        half8 a[4], bx[2], bh[2], bb[2];
        #pragma unroll
        for (int t = 0; t < 4; t++) {
            int ra = (wm + t * 16 + mr) * 32 + kqs;
            a[t] = *(const half8*)&C[ra];
        }
        #pragma unroll
        for (int t = 0; t < 2; t++) {
            int rb = (wn + t * 16 + mr) * 32 + kqs;
            bx[t] = *(const half8*)&C[8192 + rb];
            bh[t] = *(const half8*)&C[10240 + rb];
            bb[t] = *(const half8*)&C[4096 + rb];
        }
        if (k0 < 224) {
            wrS128(N, nA1, tid);
            wrS64(N + 8192, nB1, tid); wrS64(N + 10240, nB2, tid); wrS64(N + 4096, nB3, tid);
        }
        if (k0 < 192) {
            ld128(nA1, ho16, bm, 256, k0 + 64, tid);
            ld64(nB1, dxT, bn, 256, k0 + 64, tid);
            ld64(nB2, dhT, bn, 256, k0 + 64, tid);
            ld64(nB3, dbT, bn, 256, k0 + 64, tid);
        }
        #pragma unroll
        for (int tm = 0; tm < 4; tm++)
            #pragma unroll
            for (int tn = 0; tn < 2; tn++) {
                adx[tm][tn] = MFMAH(a[tm], bx[tn], adx[tm][tn], 0, 0, 0);
                adh[tm][tn] = MFMAH(a[tm], bh[tn], adh[tm][tn], 0, 0, 0);
                adb[tm][tn] = MFMAH(a[tm], bb[tn], adb[tm][tn], 0, 0, 0);
            }
        LBAR();
    }

    // epilogue: g = (adx+dxb)*(apx+bias) + (adh+dhb)*aph + (adb+dbb), stored fp16
    #pragma unroll
    for (int tn = 0; tn < 2; tn++) {
        int col = bn + wn + tn * 16 + (lane & 15);
        float bv  = ldmix(bias, col, isbf);
        float dxb = ldmix(dx_b, col, isbf);
        float dhb = ldmix(dh_b, col, isbf);
        float dbb = ldmix(db_b, col, isbf);
        #pragma unroll
        for (int tm = 0; tm < 4; tm++) {
            #pragma unroll
            for (int rr = 0; rr < 4; rr++) {
                int row = bm + wm + tm * 16 + (lane >> 4) * 4 + rr;
                float px = apx[tm][tn][rr] + bv;
                float ph = aph[tm][tn][rr];
                float dx = adx[tm][tn][rr] + dxb;
                float dh = adh[tm][tn][rr] + dhb;
                float db = adb[tm][tn][rr] + dbb;
                gp[(size_t)row * 4096 + col] = f2h(dx * px + dh * ph + db);
            }
        }
    }
}

// ---------------- LN(4096) -> gates -> c_new -> LN(1024) -> h_new ----------------
__device__ __forceinline__ void block_reduce2(float& a, float& b, float* red) {
    #pragma unroll
    for (int o = 32; o > 0; o >>= 1) {
        a += __shfl_down(a, o, 64);
        b += __shfl_down(b, o, 64);
    }
    int lane = threadIdx.x & 63, w = threadIdx.x >> 6;
    if (lane == 0) { red[w] = a; red[4 + w] = b; }
    __syncthreads();
    a = red[0] + red[1] + red[2] + red[3];
    b = red[4] + red[5] + red[6] + red[7];
    __syncthreads();
}

__global__ __launch_bounds__(256) void ln_main(const u16* __restrict__ gp,
                                               const void* __restrict__ main_c,
                                               void* __restrict__ out,
                                               const int* __restrict__ flag) {
    __shared__ float sPre[4096];
    __shared__ float sC[1024];
    __shared__ float red[8];
    int isbf = *flag;
    int b = blockIdx.x, tid = threadIdx.x;
    const u16* g = gp + (size_t)b * 4096;
    float s = 0.f, q = 0.f;
    for (int j0 = tid * 8; j0 < 4096; j0 += 2048) {
        half8 v = *(const half8*)(g + j0);
        #pragma unroll
        for (int e = 0; e < 8; e++) {
            float f = (float)v[e];
            sPre[j0 + e] = f; s += f; q += f * f;
        }
    }
    block_reduce2(s, q, red);
    float mean = s * (1.f / 4096.f);
    float var = q * (1.f / 4096.f) - mean * mean;
    float rs = rsqrtf(var + 1e-3f);
    float s2 = 0.f, q2 = 0.f;
    for (int u = tid; u < 1024; u += 256) {
        float gi = (sPre[u] - mean) * rs;
        float gf = (sPre[u + 1024] - mean) * rs;
        float gg = (sPre[u + 2048] - mean) * rs;
        float c = ldmix(main_c, (size_t)b * 1024 + u, isbf);
        float cn = sigf(gf) * c + sigf(gi) * tanhf(gg);
        sC[u] = cn;
        if (isbf) ((u16*)out)[O_C + (size_t)b * 1024 + u] = f2bf(cn);
        else      ((float*)out)[O_C + (size_t)b * 1024 + u] = cn;
        s2 += cn; q2 += cn * cn;
    }
    block_reduce2(s2, q2, red);
    float m2 = s2 * (1.f / 1024.f);
    float v2 = q2 * (1.f / 1024.f) - m2 * m2;
    float rs2 = rsqrtf(v2 + 1e-3f);
    for (int u = tid; u < 1024; u += 256) {
        float go = (sPre[u + 3072] - mean) * rs;
        float hn = sigf(go) * tanhf((sC[u] - m2) * rs2);
        if (isbf) ((u16*)out)[O_H + (size_t)b * 1024 + u] = f2bf(hn);
        else      ((float*)out)[O_H + (size_t)b * 1024 + u] = hn;
    }
}

// ---------------- launcher ----------------
extern "C" void kernel_launch(void* const* d_in, const int* in_sizes, int n_in,
                              void* d_out, int out_size, void* d_ws, size_t ws_size,
                              hipStream_t stream) {
    (void)in_sizes; (void)n_in; (void)out_size; (void)ws_size;
    const void* inputs   = d_in[0];
    const void* main_h   = d_in[1];
    const void* main_c   = d_in[2];
    const void* hyper_h  = d_in[3];
    const void* hyper_c  = d_in[4];
    const void* kernel_w = d_in[5];
    const void* rec_w    = d_in[6];
    const void* bias     = d_in[7];
    const void* hyper_k  = d_in[8];
    const void* hyper_rk = d_in[9];
    const void* hyper_b  = d_in[10];
    const void* dx_w = d_in[11];
    const void* dx_b = d_in[12];
    const void* dh_w = d_in[13];
    const void* dh_b = d_in[14];
    const void* db_w = d_in[15];
    const void* db_b = d_in[16];
    char* ws = (char*)d_ws;
    const size_t MB = 1024 * 1024;

    // workspace layout, NO overlays (ws >= 100 MB proven in r6/r7)
    int* flag = (int*)ws;
    size_t off = 256;
    u16* xh  = (u16*)(ws + off); off += 4 * MB;            // [2048,1024] fp16
    u16* mh  = (u16*)(ws + off); off += 4 * MB;            // [2048,1024] fp16
    u16* hh  = (u16*)(ws + off); off += 1 * MB;            // [2048,256]  fp16
    u16* ho  = (u16*)(ws + off); off += 1 * MB;            // [2048,256]  fp16
    u16* kT  = (u16*)(ws + off); off += 8 * MB;            // [4096,1024] fp16
    u16* rkT = (u16*)(ws + off); off += 8 * MB;            // [4096,1024] fp16
    u16* dxT = (u16*)(ws + off); off += 2 * MB;            // [4096,256]  fp16
    u16* dhT = (u16*)(ws + off); off += 2 * MB;
    u16* dbT = (u16*)(ws + off); off += 2 * MB;
    u16* BTh = (u16*)(ws + off); off += (size_t)1024 * 2304 * 2;  // 4.5 MB
    float* zbuf = (float*)(ws + off); off += 16 * MB;      // [2, 2048,1024] fp32 (split-K halves)
    u16* gp    = (u16*)(ws + off); off += 16 * MB;         // [2048,4096] fp16

    // r9: 5 launches (was 10) — prep_all fuses detect + cvt + all 4 transposes.
    prep_all<<<15872, 256, 0, stream>>>(inputs, main_h, hyper_h, hyper_k, hyper_rk,
                                        kernel_w, rec_w, dx_w, dh_w, db_w,
                                        xh, mh, hh, BTh, kT, rkT, dxT, dhT, dbT, flag);
    gemm_hyper<<<dim3(16, 16, 2), 256, 0, stream>>>(xh, mh, hh, BTh, zbuf);
    hyper_cell<<<2048, 256, 0, stream>>>(zbuf, hyper_c, hyper_b, d_out, ho, flag);
    mega_fused<<<dim3(64, 16), 256, 0, stream>>>(xh, mh, ho, kT, rkT, dxT, dhT, dbT,
                                                 bias, dx_b, dh_b, db_b, gp, flag);
    ln_main<<<2048, 256, 0, stream>>>(gp, main_c, d_out, flag);
}

// Round 10
// 259.402 us; speedup vs baseline: 1.4092x; 1.0394x over previous
//
#include <hip/hip_runtime.h>
#include <cstdint>

typedef unsigned short u16;
typedef _Float16 half8 __attribute__((ext_vector_type(8)));
typedef float floatx4 __attribute__((ext_vector_type(4)));
typedef unsigned short ushort8v __attribute__((ext_vector_type(8)));
typedef unsigned short ushort4v __attribute__((ext_vector_type(4)));
typedef float float4v __attribute__((ext_vector_type(4)));

#define BB 2048
#define UU 1024
#define HUx 256
#define O_H  0
#define O_C  (BB*UU)
#define O_HO (2*BB*UU)
#define O_HC (2*BB*UU + BB*HUx)
#define MFMAH __builtin_amdgcn_mfma_f32_16x16x32_f16

// raw barrier: ds-write visibility (lgkmcnt) without the __syncthreads vmcnt(0) drain,
// so prefetched global loads stay in flight across barriers (T3/T4 mechanism).
// sched_barrier(0) pins ordering (rule #18: hipcc can hoist reg-only ops past asm waitcnt).
#define LBAR() do { \
    asm volatile("s_waitcnt lgkmcnt(0)\n\ts_barrier" ::: "memory"); \
    __builtin_amdgcn_sched_barrier(0); \
} while (0)

__device__ __forceinline__ float bf2f(u16 u) {
    union { uint32_t i; float f; } v; v.i = ((uint32_t)u) << 16; return v.f;
}
__device__ __forceinline__ u16 f2bf(float f) {
    union { float f; uint32_t i; } v; v.f = f;
    uint32_t r = v.i + 0x7fffu + ((v.i >> 16) & 1u);
    return (u16)(r >> 16);
}
__device__ __forceinline__ u16 f2h(float f) {
    _Float16 h = (_Float16)f; u16 u; __builtin_memcpy(&u, &h, 2); return u;
}
__device__ __forceinline__ float sigf(float x) { return 1.f / (1.f + expf(-x)); }
__device__ __forceinline__ float ldmix(const void* p, size_t i, int isbf) {
    return isbf ? bf2f(((const u16*)p)[i]) : ((const float*)p)[i];
}
// load input element (bf16 or fp32) -> fp16 bits
__device__ __forceinline__ u16 ld2h(const void* p, size_t i, int isbf) {
    return f2h(ldmix(p, i, isbf));
}

// split staging: load-to-regs / write-to-LDS (prefetch pipeline; 256-thread blocks)
__device__ __forceinline__ void ld128(half8 r[2], const u16* src, int row0, int ldK,
                                      int k0, int tid) {
    #pragma unroll
    for (int i = 0; i < 2; i++) {
        int v = tid + 256 * i;
        r[i] = *(const half8*)(src + (size_t)(row0 + (v >> 2)) * ldK + k0 + (v & 3) * 8);
    }
}
__device__ __forceinline__ void ld64(half8& r, const u16* src, int row0, int ldK,
                                     int k0, int tid) {
    r = *(const half8*)(src + (size_t)(row0 + (tid >> 2)) * ldK + k0 + (tid & 3) * 8);
}
// ---- stride-40 (80B) padded layout helpers (gemm_hyper, proven r7) ----
__device__ __forceinline__ void wr128(u16* lds, const half8 r[2], int tid) {
    #pragma unroll
    for (int i = 0; i < 2; i++) {
        int v = tid + 256 * i;
        *(half8*)&lds[(v >> 2) * 40 + (v & 3) * 8] = r[i];
    }
}
__device__ __forceinline__ void wr64(u16* lds, half8 r, int tid) {
    *(half8*)&lds[(tid >> 2) * 40 + (tid & 3) * 8] = r;
}
// ---- r8: unpadded 64B-row + XOR-swizzle layout (conflict-free reads AND writes) ----
// row stride 32 u16 = 4 bank-quads; phys slot = slot ^ ((row>>1)&3).
// PROVEN r8: SQ_LDS_BANK_CONFLICT 1.52e7 -> 0.
__device__ __forceinline__ void wrS128(u16* lds, const half8 r[2], int tid) {
    #pragma unroll
    for (int i = 0; i < 2; i++) {
        int v = tid + 256 * i;
        int ps = (v & 3) ^ ((v >> 3) & 3);
        *(half8*)&lds[(v >> 2) * 32 + ps * 8] = r[i];
    }
}
__device__ __forceinline__ void wrS64(u16* lds, half8 r, int tid) {
    int ps = (tid & 3) ^ ((tid >> 3) & 3);
    *(half8*)&lds[(tid >> 2) * 32 + ps * 8] = r;
}

// ---------------- per-block dtype detect (1 = bf16, 0 = fp32) ----------------
__device__ __forceinline__ int detect_local(const u16* raw) {
    int lane = threadIdx.x & 63;
    u16 u = raw[2 * lane];
    int e = (u >> 7) & 0xFF;
    unsigned long long m = __ballot(e >= 100 && e <= 134);
    return (__popcll(m) >= 32) ? 1 : 0;
}

// ---------------- vectorized 32x32 transpose+convert tile (r10) ----------------
// 4-elem vector global loads (16B fp32 / 8B bf16) + 8B vector stores; replaces the
// scalar ld2h path (4 scalar loads + 4 scalar 2B stores per thread).
__device__ __forceinline__ void transpose_tile_v(const void* in, u16* out, int C,
                                                 int ostride, int ocol, int r0, int c0,
                                                 int isbf, u16* th /*[32*36]*/) {
    int tid = threadIdx.x;
    int ty = tid >> 3, tx4 = (tid & 7) * 4;
    ushort4v v;
    if (isbf) {
        ushort4v q = *(const ushort4v*)((const u16*)in + (size_t)(r0 + ty) * C + c0 + tx4);
        #pragma unroll
        for (int j = 0; j < 4; j++) v[j] = f2h(bf2f(q[j]));
    } else {
        float4v q = *(const float4v*)((const float*)in + (size_t)(r0 + ty) * C + c0 + tx4);
        #pragma unroll
        for (int j = 0; j < 4; j++) v[j] = f2h(q[j]);
    }
    *(ushort4v*)&th[ty * 36 + tx4] = v;
    __syncthreads();
    ushort4v w;
    #pragma unroll
    for (int j = 0; j < 4; j++) w[j] = th[(tx4 + j) * 36 + ty];
    *(ushort4v*)(out + (size_t)(c0 + ty) * ostride + ocol + r0 + tx4) = w;
}

// ---------------- prep_in: dtype-detect + input cvt + hyper-weight (BTh) transpose ----------------
// 4608 blocks: [0,2304) cvt, [2304,4352) hyper_k, [4352,4608) hyper_rk.
__global__ __launch_bounds__(256) void prep_in(
    const void* __restrict__ xs, const void* __restrict__ ms, const void* __restrict__ hs,
    const void* __restrict__ hyper_k, const void* __restrict__ hyper_rk,
    u16* __restrict__ xh, u16* __restrict__ mh, u16* __restrict__ hh,
    u16* __restrict__ BTh, int* __restrict__ flag) {
    __shared__ __align__(16) u16 th[32 * 36];
    int bid = blockIdx.x, tid = threadIdx.x;
    int isbf = detect_local((const u16*)xs);
    if (bid == 0 && tid == 0) *flag = isbf;

    if (bid < 2304) {
        // cvt role: vectorized loads + single 16B store per thread (r9-proven)
        int i = bid * 256 + tid;
        const void* src; u16* dst; int t;
        if (i < 262144)      { src = xs; dst = xh; t = i; }
        else if (i < 524288) { src = ms; dst = mh; t = i - 262144; }
        else                 { src = hs; dst = hh; t = i - 524288; }  // < 589824
        half8 o;
        if (isbf) {
            ushort8v v = *(const ushort8v*)((const u16*)src + (size_t)t * 8);
            #pragma unroll
            for (int j = 0; j < 8; j++) o[j] = (_Float16)bf2f(v[j]);
        } else {
            float4v a = *(const float4v*)((const float*)src + (size_t)t * 8);
            float4v b = *(const float4v*)((const float*)src + (size_t)t * 8 + 4);
            #pragma unroll
            for (int j = 0; j < 4; j++) { o[j] = (_Float16)a[j]; o[j + 4] = (_Float16)b[j]; }
        }
        *(half8*)(dst + (size_t)t * 8) = o;
    } else if (bid < 4352) {
        int u = bid - 2304;
        transpose_tile_v(hyper_k, BTh, 1024, 2304, 0, (u >> 5) * 32, (u & 31) * 32, isbf, th);
    } else {
        int u = bid - 4352;
        transpose_tile_v(hyper_rk, BTh, 1024, 2304, 2048, (u >> 5) * 32, (u & 31) * 32, isbf, th);
    }
}

// ---------------- hyper GEMM fused with mega-weight transposes (r10) ----------------
// bids [0,512): the r4-proven gemm (split-K x2, reg-prefetch + LBAR pipeline).
// bids [512,12288): kT/rkT/dxT/dhT/dbT transposes — pure-BW blocks that fill the
// CUs while the latency-bound gemm (12% HBM) runs -> transpose traffic rides free.
// Outputs consumed 2 launches later (mega) -> no intra-launch dependency.
__device__ __forceinline__ void gh_load(half8 pA[2], half8& pB,
                                        const u16* xh, const u16* mh, const u16* hh,
                                        const u16* BT, int bm, int bn, int s, int tid) {
    const u16* Ap; int ldA, kA;
    if (s < 32)      { Ap = xh; ldA = 1024; kA = s * 32; }
    else if (s < 64) { Ap = mh; ldA = 1024; kA = (s - 32) * 32; }
    else             { Ap = hh; ldA = 256;  kA = (s - 64) * 32; }
    ld128(pA, Ap, bm, ldA, kA, tid);
    ld64(pB, BT, bn, 2304, s * 32, tid);
}

__global__ __launch_bounds__(256) void gemm_hyper_wt(
    const u16* __restrict__ xh, const u16* __restrict__ mh, const u16* __restrict__ hh,
    const u16* __restrict__ BT, float* __restrict__ z,
    const void* __restrict__ xs,
    const void* __restrict__ kernel_w, const void* __restrict__ rec_w,
    const void* __restrict__ dx_w, const void* __restrict__ dh_w,
    const void* __restrict__ db_w,
    u16* __restrict__ kT, u16* __restrict__ rkT,
    u16* __restrict__ dxT, u16* __restrict__ dhT, u16* __restrict__ dbT) {
    __shared__ __align__(16) u16 sA[128 * 40];
    __shared__ __align__(16) u16 sB[64 * 40];
    int bid = blockIdx.x, tid = threadIdx.x;

    if (bid >= 512) {
        // ---- weight-transpose role ----
        int isbf = detect_local((const u16*)xs);
        int u = bid - 512;
        const void* in; u16* out; int ostride, r0, c0;
        if (u < 8192) {
            in  = (u < 4096) ? kernel_w : rec_w;
            out = (u < 4096) ? kT : rkT;
            int r = u & 4095;
            ostride = 1024; r0 = (r >> 7) * 32; c0 = (r & 127) * 32;
        } else {
            int v = u - 8192;
            int zi = v >> 10, r = v & 1023;
            in  = (zi == 0) ? dx_w : (zi == 1) ? dh_w : db_w;
            out = (zi == 0) ? dxT : (zi == 1) ? dhT : dbT;
            ostride = 256; r0 = (r >> 7) * 32; c0 = (r & 127) * 32;
        }
        transpose_tile_v(in, out, 4096, ostride, 0, r0, c0, isbf, sA);
        return;
    }

    // ---- gemm role (identical to r4/r9 gemm_hyper) ----
    int bxv = bid & 15, byv = (bid >> 4) & 15, bzv = bid >> 8;
    int lane = tid & 63, wave = tid >> 6;
    int wm = (wave & 1) * 64, wn = (wave >> 1) * 32;
    int bm = byv * 128, bn = bxv * 64;
    int s0 = bzv * 36, s1 = s0 + 36;
    floatx4 acc[4][2] = {};
    int mr = lane & 15, kq = (lane >> 4) * 8;

    half8 pA[2]; half8 pB;
    gh_load(pA, pB, xh, mh, hh, BT, bm, bn, s0, tid);
    wr128(sA, pA, tid); wr64(sB, pB, tid);
    gh_load(pA, pB, xh, mh, hh, BT, bm, bn, s0 + 1, tid);
    LBAR();

    #pragma unroll 1
    for (int s = s0; s < s1; s++) {
        half8 a[4], b[2];
        #pragma unroll
        for (int t = 0; t < 4; t++) a[t] = *(const half8*)&sA[(wm + t * 16 + mr) * 40 + kq];
        #pragma unroll
        for (int t = 0; t < 2; t++) b[t] = *(const half8*)&sB[(wn + t * 16 + mr) * 40 + kq];
        #pragma unroll
        for (int tm = 0; tm < 4; tm++)
            #pragma unroll
            for (int tn = 0; tn < 2; tn++)
                acc[tm][tn] = MFMAH(a[tm], b[tn], acc[tm][tn], 0, 0, 0);
        LBAR();  // all waves done reading LDS -> safe to overwrite
        if (s < s1 - 1) {
            wr128(sA, pA, tid); wr64(sB, pB, tid);
            if (s < s1 - 2)
                gh_load(pA, pB, xh, mh, hh, BT, bm, bn, s + 2, tid);
            LBAR();  // writes visible
        }
    }

    float* zp = z + (size_t)bzv * 2048 * 1024;
    #pragma unroll
    for (int tm = 0; tm < 4; tm++)
        #pragma unroll
        for (int tn = 0; tn < 2; tn++) {
            int col = bn + wn + tn * 16 + (lane & 15);
            #pragma unroll
            for (int rr = 0; rr < 4; rr++) {
                int row = bm + wm + tm * 16 + (lane >> 4) * 4 + rr;
                zp[(size_t)row * 1024 + col] = acc[tm][tn][rr];
            }
        }
}

// ---------------- hyper LSTM cell (sums split-K halves); ho stored fp16 ----------------
__global__ void hyper_cell(const float* __restrict__ z, const void* __restrict__ hyper_c,
                           const void* __restrict__ hyper_bias, void* __restrict__ out,
                           u16* __restrict__ ho16, const int* __restrict__ flag) {
    int isbf = *flag;
    int t = blockIdx.x * 256 + threadIdx.x;
    int k = t & 255;
    const float* zr  = z + (size_t)(t >> 8) * 1024;
    const float* zr2 = zr + (size_t)2048 * 1024;
    float hi = zr[k]       + zr2[k]       + ldmix(hyper_bias, k, isbf);
    float hf = zr[k + 256] + zr2[k + 256] + ldmix(hyper_bias, k + 256, isbf);
    float hg = zr[k + 512] + zr2[k + 512] + ldmix(hyper_bias, k + 512, isbf);
    float ho = zr[k + 768] + zr2[k + 768] + ldmix(hyper_bias, k + 768, isbf);
    float c  = ldmix(hyper_c, t, isbf);
    float cn = sigf(hf) * c + sigf(hi) * tanhf(hg);
    float hout = sigf(ho) * tanhf(cn);
    ho16[t] = f2h(hout);
    if (isbf) {
        ((u16*)out)[O_HO + t] = f2bf(hout);
        ((u16*)out)[O_HC + t] = f2bf(cn);
    } else {
        ((float*)out)[O_HO + t] = hout;
        ((float*)out)[O_HC + t] = cn;
    }
}

// ---------------- fused gates GEMM (fp16, 5 acc sets) -> gates_pre fp16 ----------------
// block 128M x 64N, waves 2(M)x2(N), wave tile 64x32 PER SET.
// r7: LDS double-buffer, 1 LBAR/step, reg-prefetch dist 1 (87.8us).
// r8: XOR-swizzle layout -> bank conflicts 1.52e7 -> 0; 80.3us, MfmaUtil 24.8%.
// UNCHANGED since r8.
__global__ __launch_bounds__(256, 2) void mega_fused(
    const u16* __restrict__ xh, const u16* __restrict__ mh, const u16* __restrict__ ho16,
    const u16* __restrict__ kT, const u16* __restrict__ rkT,
    const u16* __restrict__ dxT, const u16* __restrict__ dhT, const u16* __restrict__ dbT,
    const void* __restrict__ bias, const void* __restrict__ dx_b,
    const void* __restrict__ dh_b, const void* __restrict__ db_b,
    u16* __restrict__ gp, const int* __restrict__ flag) {
    __shared__ __align__(16) u16 S[2][12288];
    int isbf = *flag;
    int tid = threadIdx.x, lane = tid & 63, wave = tid >> 6;
    int wm = (wave & 1) * 64, wn = (wave >> 1) * 32;
    int bm = blockIdx.y * 128, bn = blockIdx.x * 64;
    floatx4 apx[4][2] = {}, aph[4][2] = {}, adx[4][2] = {}, adh[4][2] = {}, adb[4][2] = {};
    int mr = lane & 15;
    // swizzled k-chunk offset: phys slot = (lane>>4) ^ ((row>>1)&3); row>>1&3 == mr>>1&3
    // (wm/wn/t*16 are multiples of 16 -> contribute 0). Same involution as wrS*.
    int kqs = (((lane >> 4) ^ ((mr >> 1) & 3))) * 8;

    half8 nA1[2], nA2[2], nB1, nB2, nB3;

    // ---- prologue: tile0 -> regs -> buf0 ; tile1 -> regs ; barrier ----
    ld128(nA1, xh,  bm, 1024, 0, tid);
    ld128(nA2, mh,  bm, 1024, 0, tid);
    ld64(nB1, kT,  bn, 1024, 0, tid);
    ld64(nB2, rkT, bn, 1024, 0, tid);
    wrS128(S[0], nA1, tid); wrS128(S[0] + 4096, nA2, tid);
    wrS64(S[0] + 8192, nB1, tid); wrS64(S[0] + 10240, nB2, tid);
    ld128(nA1, xh,  bm, 1024, 32, tid);
    ld128(nA2, mh,  bm, 1024, 32, tid);
    ld64(nB1, kT,  bn, 1024, 32, tid);
    ld64(nB2, rkT, bn, 1024, 32, tid);
    LBAR();

    // ---- phase 1: px = x@kT, ph = mh@rkT  (K=1024), 1 barrier/step ----
    #pragma unroll 1
    for (int k0 = 0; k0 < 1024; k0 += 32) {
        int p = (k0 >> 5) & 1;
        const u16* C = S[p];
        u16* N = S[p ^ 1];
        half8 ax[4], am[4], bk[2], br[2];
        #pragma unroll
        for (int t = 0; t < 4; t++) {
            int ra = (wm + t * 16 + mr) * 32 + kqs;
            ax[t] = *(const half8*)&C[ra];
            am[t] = *(const half8*)&C[4096 + ra];
        }
        #pragma unroll
        for (int t = 0; t < 2; t++) {
            int rb = (wn + t * 16 + mr) * 32 + kqs;
            bk[t] = *(const half8*)&C[8192 + rb];
            br[t] = *(const half8*)&C[10240 + rb];
        }
        // stage next tile (in regs) into the other buffer — overlaps MFMA below
        if (k0 < 992) {
            wrS128(N, nA1, tid); wrS128(N + 4096, nA2, tid);
            wrS64(N + 8192, nB1, tid); wrS64(N + 10240, nB2, tid);
        } else {
            // last ph1 step: stage PHASE-2 tile0 (loaded at k0==960), phase2 layout
            wrS128(N, nA1, tid);
            wrS64(N + 8192, nB1, tid); wrS64(N + 10240, nB2, tid); wrS64(N + 4096, nB3, tid);
        }
        // prefetch tile k0+64 into regs
        if (k0 < 960) {
            ld128(nA1, xh,  bm, 1024, k0 + 64, tid);
            ld128(nA2, mh,  bm, 1024, k0 + 64, tid);
            ld64(nB1, kT,  bn, 1024, k0 + 64, tid);
            ld64(nB2, rkT, bn, 1024, k0 + 64, tid);
        } else if (k0 == 960) {
            ld128(nA1, ho16, bm, 256, 0, tid);
            ld64(nB1, dxT, bn, 256, 0, tid);
            ld64(nB2, dhT, bn, 256, 0, tid);
            ld64(nB3, dbT, bn, 256, 0, tid);
        } else {  // k0 == 992: phase-2 tile1
            ld128(nA1, ho16, bm, 256, 32, tid);
            ld64(nB1, dxT, bn, 256, 32, tid);
            ld64(nB2, dhT, bn, 256, 32, tid);
            ld64(nB3, dbT, bn, 256, 32, tid);
        }
        #pragma unroll
        for (int tm = 0; tm < 4; tm++)
            #pragma unroll
            for (int tn = 0; tn < 2; tn++) {
                apx[tm][tn] = MFMAH(ax[tm], bk[tn], apx[tm][tn], 0, 0, 0);
                aph[tm][tn] = MFMAH(am[tm], br[tn], aph[tm][tn], 0, 0, 0);
            }
        LBAR();
    }

    // ---- phase 2: d_* = ho @ {dxT,dhT,dbT}  (K=256); A shared by 3 sets ----
    #pragma unroll 1
    for (int k0 = 0; k0 < 256; k0 += 32) {
        int p = (k0 >> 5) & 1;
        const u16* C = S[p];
        u16* N = S[p ^ 1];
        half8 a[4], bx[2], bh[2], bb[2];
        #pragma unroll
        for (int t = 0; t < 4; t++) {
            int ra = (wm + t * 16 + mr) * 32 + kqs;
            a[t] = *(const half8*)&C[ra];
        }
        #pragma unroll
        for (int t = 0; t < 2; t++) {
            int rb = (wn + t * 16 + mr) * 32 + kqs;
            bx[t] = *(const half8*)&C[8192 + rb];
            bh[t] = *(const half8*)&C[10240 + rb];
            bb[t] = *(const half8*)&C[4096 + rb];
        }
        if (k0 < 224) {
            wrS128(N, nA1, tid);
            wrS64(N + 8192, nB1, tid); wrS64(N + 10240, nB2, tid); wrS64(N + 4096, nB3, tid);
        }
        if (k0 < 192) {
            ld128(nA1, ho16, bm, 256, k0 + 64, tid);
            ld64(nB1, dxT, bn, 256, k0 + 64, tid);
            ld64(nB2, dhT, bn, 256, k0 + 64, tid);
            ld64(nB3, dbT, bn, 256, k0 + 64, tid);
        }
        #pragma unroll
        for (int tm = 0; tm < 4; tm++)
            #pragma unroll
            for (int tn = 0; tn < 2; tn++) {
                adx[tm][tn] = MFMAH(a[tm], bx[tn], adx[tm][tn], 0, 0, 0);
                adh[tm][tn] = MFMAH(a[tm], bh[tn], adh[tm][tn], 0, 0, 0);
                adb[tm][tn] = MFMAH(a[tm], bb[tn], adb[tm][tn], 0, 0, 0);
            }
        LBAR();
    }

    // epilogue: g = (adx+dxb)*(apx+bias) + (adh+dhb)*aph + (adb+dbb), stored fp16
    #pragma unroll
    for (int tn = 0; tn < 2; tn++) {
        int col = bn + wn + tn * 16 + (lane & 15);
        float bv  = ldmix(bias, col, isbf);
        float dxb = ldmix(dx_b, col, isbf);
        float dhb = ldmix(dh_b, col, isbf);
        float dbb = ldmix(db_b, col, isbf);
        #pragma unroll
        for (int tm = 0; tm < 4; tm++) {
            #pragma unroll
            for (int rr = 0; rr < 4; rr++) {
                int row = bm + wm + tm * 16 + (lane >> 4) * 4 + rr;
                float px = apx[tm][tn][rr] + bv;
                float ph = aph[tm][tn][rr];
                float dx = adx[tm][tn][rr] + dxb;
                float dh = adh[tm][tn][rr] + dhb;
                float db = adb[tm][tn][rr] + dbb;
                gp[(size_t)row * 4096 + col] = f2h(dx * px + dh * ph + db);
            }
        }
    }
}

// ---------------- LN(4096) -> gates -> c_new -> LN(1024) -> h_new ----------------
__device__ __forceinline__ void block_reduce2(float& a, float& b, float* red) {
    #pragma unroll
    for (int o = 32; o > 0; o >>= 1) {
        a += __shfl_down(a, o, 64);
        b += __shfl_down(b, o, 64);
    }
    int lane = threadIdx.x & 63, w = threadIdx.x >> 6;
    if (lane == 0) { red[w] = a; red[4 + w] = b; }
    __syncthreads();
    a = red[0] + red[1] + red[2] + red[3];
    b = red[4] + red[5] + red[6] + red[7];
    __syncthreads();
}

__global__ __launch_bounds__(256) void ln_main(const u16* __restrict__ gp,
                                               const void* __restrict__ main_c,
                                               void* __restrict__ out,
                                               const int* __restrict__ flag) {
    __shared__ float sPre[4096];
    __shared__ float sC[1024];
    __shared__ float red[8];
    int isbf = *flag;
    int b = blockIdx.x, tid = threadIdx.x;
    const u16* g = gp + (size_t)b * 4096;
    float s = 0.f, q = 0.f;
    for (int j0 = tid * 8; j0 < 4096; j0 += 2048) {
        half8 v = *(const half8*)(g + j0);
        #pragma unroll
        for (int e = 0; e < 8; e++) {
            float f = (float)v[e];
            sPre[j0 + e] = f; s += f; q += f * f;
        }
    }
    block_reduce2(s, q, red);
    float mean = s * (1.f / 4096.f);
    float var = q * (1.f / 4096.f) - mean * mean;
    float rs = rsqrtf(var + 1e-3f);
    float s2 = 0.f, q2 = 0.f;
    for (int u = tid; u < 1024; u += 256) {
        float gi = (sPre[u] - mean) * rs;
        float gf = (sPre[u + 1024] - mean) * rs;
        float gg = (sPre[u + 2048] - mean) * rs;
        float c = ldmix(main_c, (size_t)b * 1024 + u, isbf);
        float cn = sigf(gf) * c + sigf(gi) * tanhf(gg);
        sC[u] = cn;
        if (isbf) ((u16*)out)[O_C + (size_t)b * 1024 + u] = f2bf(cn);
        else      ((float*)out)[O_C + (size_t)b * 1024 + u] = cn;
        s2 += cn; q2 += cn * cn;
    }
    block_reduce2(s2, q2, red);
    float m2 = s2 * (1.f / 1024.f);
    float v2 = q2 * (1.f / 1024.f) - m2 * m2;
    float rs2 = rsqrtf(v2 + 1e-3f);
    for (int u = tid; u < 1024; u += 256) {
        float go = (sPre[u + 3072] - mean) * rs;
        float hn = sigf(go) * tanhf((sC[u] - m2) * rs2);
        if (isbf) ((u16*)out)[O_H + (size_t)b * 1024 + u] = f2bf(hn);
        else      ((float*)out)[O_H + (size_t)b * 1024 + u] = hn;
    }
}

// ---------------- launcher ----------------
extern "C" void kernel_launch(void* const* d_in, const int* in_sizes, int n_in,
                              void* d_out, int out_size, void* d_ws, size_t ws_size,
                              hipStream_t stream) {
    (void)in_sizes; (void)n_in; (void)out_size; (void)ws_size;
    const void* inputs   = d_in[0];
    const void* main_h   = d_in[1];
    const void* main_c   = d_in[2];
    const void* hyper_h  = d_in[3];
    const void* hyper_c  = d_in[4];
    const void* kernel_w = d_in[5];
    const void* rec_w    = d_in[6];
    const void* bias     = d_in[7];
    const void* hyper_k  = d_in[8];
    const void* hyper_rk = d_in[9];
    const void* hyper_b  = d_in[10];
    const void* dx_w = d_in[11];
    const void* dx_b = d_in[12];
    const void* dh_w = d_in[13];
    const void* dh_b = d_in[14];
    const void* db_w = d_in[15];
    const void* db_b = d_in[16];
    char* ws = (char*)d_ws;
    const size_t MB = 1024 * 1024;

    // workspace layout, NO overlays (ws >= 100 MB proven in r6/r7)
    int* flag = (int*)ws;
    size_t off = 256;
    u16* xh  = (u16*)(ws + off); off += 4 * MB;            // [2048,1024] fp16
    u16* mh  = (u16*)(ws + off); off += 4 * MB;            // [2048,1024] fp16
    u16* hh  = (u16*)(ws + off); off += 1 * MB;            // [2048,256]  fp16
    u16* ho  = (u16*)(ws + off); off += 1 * MB;            // [2048,256]  fp16
    u16* kT  = (u16*)(ws + off); off += 8 * MB;            // [4096,1024] fp16
    u16* rkT = (u16*)(ws + off); off += 8 * MB;            // [4096,1024] fp16
    u16* dxT = (u16*)(ws + off); off += 2 * MB;            // [4096,256]  fp16
    u16* dhT = (u16*)(ws + off); off += 2 * MB;
    u16* dbT = (u16*)(ws + off); off += 2 * MB;
    u16* BTh = (u16*)(ws + off); off += (size_t)1024 * 2304 * 2;  // 4.5 MB
    float* zbuf = (float*)(ws + off); off += 16 * MB;      // [2, 2048,1024] fp32 (split-K halves)
    u16* gp    = (u16*)(ws + off); off += 16 * MB;         // [2048,4096] fp16

    // r10: 5 launches — weight transposes ride inside the gemm launch.
    prep_in<<<4608, 256, 0, stream>>>(inputs, main_h, hyper_h, hyper_k, hyper_rk,
                                      xh, mh, hh, BTh, flag);
    gemm_hyper_wt<<<12288, 256, 0, stream>>>(xh, mh, hh, BTh, zbuf, inputs,
                                             kernel_w, rec_w, dx_w, dh_w, db_w,
                                             kT, rkT, dxT, dhT, dbT);
    hyper_cell<<<2048, 256, 0, stream>>>(zbuf, hyper_c, hyper_b, d_out, ho, flag);
    mega_fused<<<dim3(64, 16), 256, 0, stream>>>(xh, mh, ho, kT, rkT, dxT, dhT, dbT,
                                                 bias, dx_b, dh_b, db_b, gp, flag);
    ln_main<<<2048, 256, 0, stream>>>(gp, main_c, d_out, flag);
}